// Round 9
// baseline (1247.375 us; speedup 1.0000x reference)
//
#include <hip/hip_runtime.h>

#define NN 200000
#define EE 800000
#define GG 2048
#define NBLK ((NN + 255) / 256)   // 782

typedef __attribute__((ext_vector_type(8))) short short8;
typedef __attribute__((ext_vector_type(4))) float f32x4;

__device__ __forceinline__ float bf2f(ushort u){
  unsigned x = ((unsigned)u) << 16;
  return __uint_as_float(x);
}
__device__ __forceinline__ ushort f2bf(float f){
  unsigned x = __float_as_uint(f);
  x += 0x7fffu + ((x >> 16) & 1u);
  return (ushort)(x >> 16);
}

// swizzle a 256xK fp32 weight into MFMA B-fragment order (K=256)
__device__ __forceinline__ void swz256(const float* __restrict__ W, ushort* __restrict__ o, int idx){
  int ks = idx >> 13, rem = idx & 8191;
  int j16 = rem >> 9, rem2 = rem & 511;
  int ln = rem2 >> 3, t = rem2 & 7;
  int row = j16*16 + (ln & 15);
  int k = ks*32 + (ln >> 4)*8 + t;
  o[idx] = f2bf(W[(size_t)row*256 + k]);
}

// ---------------- prep: weight conversion/swizzle + edge-bias tables ----------------
__global__ __launch_bounds__(256) void prep_k(
    const float* __restrict__ W10, const float* __restrict__ W20,
    const float* __restrict__ W11, const float* __restrict__ W21,
    const float* __restrict__ W12, const float* __restrict__ W22,
    const float* __restrict__ lw0, const float* __restrict__ lb0,
    const float* __restrict__ lw1, const float* __restrict__ lb1,
    const float* __restrict__ lw2, const float* __restrict__ lb2,
    const float* __restrict__ eE, const float* __restrict__ mW1,
    const float* __restrict__ mW2,
    ushort* __restrict__ wb10, ushort* __restrict__ wb20,
    ushort* __restrict__ wb11, ushort* __restrict__ wb21,
    ushort* __restrict__ wb12, ushort* __restrict__ wb22,
    ushort* __restrict__ mW1b, ushort* __restrict__ mW2b,
    float* __restrict__ eb)
{
  int b = blockIdx.x, tid = threadIdx.x;
  if (b < 64){ // W1_0 (256x44) -> B-frag swizzled 256x64 (2 kslices), zero-padded
    int idx = b*256 + tid;
    int ks = idx >> 13, rem = idx & 8191;
    int j16 = rem >> 9, rem2 = rem & 511;
    int ln = rem2 >> 3, t = rem2 & 7;
    int row = j16*16 + (ln & 15);
    int k = ks*32 + (ln >> 4)*8 + t;
    wb10[idx] = (k < 44) ? f2bf(W10[row*44 + k]) : (ushort)0;
    return;
  }
  b -= 64;
  if (b < 256){ swz256(W20, wb20, b*256+tid); return; } b -= 256;
  if (b < 256){ swz256(W11, wb11, b*256+tid); return; } b -= 256;
  if (b < 256){ swz256(W21, wb21, b*256+tid); return; } b -= 256;
  if (b < 256){ swz256(W12, wb12, b*256+tid); return; } b -= 256;
  if (b < 256){ swz256(W22, wb22, b*256+tid); return; } b -= 256;
  if (b < 384){ // mW1 (256x323) -> padded row-major (256x384)
    int idx = b*256 + tid; int o = idx / 384, k = idx - o*384;
    mW1b[idx] = (k < 323) ? f2bf(mW1[(size_t)o*323 + k]) : (ushort)0;
    return;
  }
  b -= 384;
  if (b < 512){ int idx = b*256+tid; mW2b[idx] = f2bf(mW2[idx]); return; } b -= 512;
  int li = b >> 2, t = b & 3;
  const float* lw = (li == 0) ? lw0 : ((li == 1) ? lw1 : lw2);
  const float* lb = (li == 0) ? lb0 : ((li == 1) ? lb1 : lb2);
  int d = (li == 0) ? 44 : 256;
  float v = 0.f;
  if (tid < d){
    float a = 0.f;
    #pragma unroll
    for (int j = 0; j < 16; j++) a += eE[t*16 + j] * lw[tid*16 + j];
    v = a + lb[tid];
  }
  eb[(li*4 + t)*256 + tid] = v;
}

// ---------------- h0 = [op_embed[op], nums, 0-pad] as bf16 N x 64 ----------------
__global__ __launch_bounds__(256) void build_h0_k(
    const float* __restrict__ x, const float* __restrict__ opE, ushort* __restrict__ h0)
{
  int idx = blockIdx.x*256 + threadIdx.x;
  int i = idx >> 6, c = idx & 63;
  float v = 0.f;
  if (c < 32){
    int op = (int)x[(size_t)i*13];
    op = op < 0 ? 0 : (op > 63 ? 63 : op);
    v = opE[op*32 + c];
  } else if (c < 44){
    v = x[(size_t)i*13 + (c - 31)];
  }
  h0[idx] = f2bf(v);
}

// ================= CSR build =================
__global__ __launch_bounds__(256) void deg_k(const int* __restrict__ dst, int* __restrict__ D){
  int e = blockIdx.x*256 + threadIdx.x;
  atomicAdd(&D[dst[e]], 1);
}
__global__ __launch_bounds__(256) void scan1_k(int* __restrict__ D, int* __restrict__ bsum){
  __shared__ int s[256];
  int b = blockIdx.x, t = threadIdx.x, idx = b*256 + t;
  int v = (idx < NN) ? D[idx] : 0;
  s[t] = v; __syncthreads();
  for (int off = 1; off < 256; off <<= 1){
    int u = (t >= off) ? s[t-off] : 0;
    __syncthreads();
    s[t] += u;
    __syncthreads();
  }
  if (idx < NN) D[idx] = s[t] - v;
  if (t == 255) bsum[b] = s[255];
}
__global__ __launch_bounds__(256) void scan2_k(int* __restrict__ bsum){
  __shared__ int s[256];
  __shared__ int carry;
  int t = threadIdx.x;
  if (t == 0) carry = 0;
  __syncthreads();
  for (int c0 = 0; c0 < NBLK; c0 += 256){
    int idx = c0 + t;
    int v = (idx < NBLK) ? bsum[idx] : 0;
    s[t] = v; __syncthreads();
    for (int off = 1; off < 256; off <<= 1){
      int u = (t >= off) ? s[t-off] : 0;
      __syncthreads();
      s[t] += u;
      __syncthreads();
    }
    int ex = s[t] - v + carry;
    if (idx < NBLK) bsum[idx] = ex;
    int tot = s[255];
    __syncthreads();
    if (t == 0) carry += tot;
    __syncthreads();
  }
}
__global__ __launch_bounds__(256) void scan3_k(int* __restrict__ D, const int* __restrict__ bsum){
  int b = blockIdx.x, idx = b*256 + threadIdx.x;
  if (idx < NN) D[idx] += bsum[b];
}
__global__ __launch_bounds__(256) void fill_k(const int* __restrict__ src, const int* __restrict__ dst,
                                              const int* __restrict__ et, int* __restrict__ D,
                                              int* __restrict__ csr){
  int e = blockIdx.x*256 + threadIdx.x;
  int d = dst[e];
  int t = et[e]; t = t < 3 ? t : 3;
  int pos = atomicAdd(&D[d], 1);
  csr[pos] = src[e] | (t << 18);
}

// ---------------- fused layer (R8 production structure, unchanged) ----------------
template<int KD, int RESID>
__global__ __launch_bounds__(256) void layerf_k(
    const ushort* __restrict__ hsrc, const int* __restrict__ Dend, const int* __restrict__ csr,
    const float* __restrict__ ebL,
    const ushort* __restrict__ W1s, const float* __restrict__ b1,
    const ushort* __restrict__ W2s, const float* __restrict__ b2,
    const float* __restrict__ epsp, ushort* __restrict__ hout)
{
  __shared__ ushort ZT[32][264];
  __shared__ ushort HT[RESID ? 32 : 1][264];   // raw h_in tile for the residual
  __shared__ float ebs[1024];
  __shared__ float red1[32][4], red2[32][4], mnL[32], rsL[32];
  const int tid = threadIdx.x, lane = tid & 63, wv = tid >> 6;
  const int l15 = lane & 15, lq = lane >> 4;
  const int rowBase = blockIdx.x * 32;
  const float epv = 1.0f + epsp[0];
  const char* hb = (const char*)hsrc;

  if (KD == 256){
    for (int i = tid; i < 1024; i += 256) ebs[i] = ebL[i];
  } else {
    if (tid < 256) ebs[tid] = ebL[(tid >> 6)*256 + (tid & 63)];  // compact [4][64]
  }
  __syncthreads();

  // ---- A: z = (1+eps)h[r] + sum_e relu(h[src]+eb[et]) -> ZT ----
  if (KD == 256){
    int nz; asm("v_mov_b32 %0, 0" : "=v"(nz));
    const int c = lane * 4;
    const unsigned c2 = lane * 8;
    #pragma unroll 1
    for (int it = 0; it < 2; it++){
      int rr0 = wv*8 + it*4;
      int r0 = rowBase + rr0;
      float4 A0, A1, A2, A3;
      {
        ushort4 q0 = *(const ushort4*)(hb + (size_t)(r0+0)*512 + c2);
        ushort4 q1 = *(const ushort4*)(hb + (size_t)(r0+1)*512 + c2);
        ushort4 q2 = *(const ushort4*)(hb + (size_t)(r0+2)*512 + c2);
        ushort4 q3 = *(const ushort4*)(hb + (size_t)(r0+3)*512 + c2);
        if (RESID){
          *(ushort4*)&HT[rr0+0][c] = q0;
          *(ushort4*)&HT[rr0+1][c] = q1;
          *(ushort4*)&HT[rr0+2][c] = q2;
          *(ushort4*)&HT[rr0+3][c] = q3;
        }
        A0 = make_float4(epv*bf2f(q0.x), epv*bf2f(q0.y), epv*bf2f(q0.z), epv*bf2f(q0.w));
        A1 = make_float4(epv*bf2f(q1.x), epv*bf2f(q1.y), epv*bf2f(q1.z), epv*bf2f(q1.w));
        A2 = make_float4(epv*bf2f(q2.x), epv*bf2f(q2.y), epv*bf2f(q2.z), epv*bf2f(q2.w));
        A3 = make_float4(epv*bf2f(q3.x), epv*bf2f(q3.y), epv*bf2f(q3.z), epv*bf2f(q3.w));
      }
      int bm1 = (r0 == 0) ? 0 : Dend[r0-1];
      int e0 = Dend[r0], e1 = Dend[r0+1], e2 = Dend[r0+2], e3 = Dend[r0+3];
      int st0 = bm1, st1 = e0, st2 = e1, st3 = e2;
      int n0 = e0 - st0, n1 = e1 - st1, n2 = e2 - st2, n3 = e3 - st3;
      int nmax = n0 > n1 ? n0 : n1;
      nmax = nmax > n2 ? nmax : n2;
      nmax = nmax > n3 ? nmax : n3;
      ushort4 z4; z4.x = z4.y = z4.z = z4.w = 0;
      ushort4 sv0 = z4, sv1 = z4, sv2 = z4, sv3 = z4;
      int t0 = 0, t1 = 0, t2 = 0, t3 = 0;
      int q0 = 0, q1 = 0, q2 = 0, q3 = 0;
      if (n0 > 0){ int p = csr[st0 + nz]; sv0 = *(const ushort4*)(hb + (unsigned)((p & 0x3FFFF) << 9) + c2); t0 = ((p >> 18) & 3)*256; }
      if (n1 > 0){ int p = csr[st1 + nz]; sv1 = *(const ushort4*)(hb + (unsigned)((p & 0x3FFFF) << 9) + c2); t1 = ((p >> 18) & 3)*256; }
      if (n2 > 0){ int p = csr[st2 + nz]; sv2 = *(const ushort4*)(hb + (unsigned)((p & 0x3FFFF) << 9) + c2); t2 = ((p >> 18) & 3)*256; }
      if (n3 > 0){ int p = csr[st3 + nz]; sv3 = *(const ushort4*)(hb + (unsigned)((p & 0x3FFFF) << 9) + c2); t3 = ((p >> 18) & 3)*256; }
      if (n0 > 1) q0 = csr[st0 + 1 + nz];
      if (n1 > 1) q1 = csr[st1 + 1 + nz];
      if (n2 > 1) q2 = csr[st2 + 1 + nz];
      if (n3 > 1) q3 = csr[st3 + 1 + nz];
      for (int k = 0; k < nmax; k++){
        ushort4 c0 = sv0, c1 = sv1, c2v = sv2, c3 = sv3;
        int u0 = t0, u1 = t1, u2 = t2, u3 = t3;
        if (k+1 < n0){ int p = q0; sv0 = *(const ushort4*)(hb + (unsigned)((p & 0x3FFFF) << 9) + c2); t0 = ((p >> 18) & 3)*256; if (k+2 < n0) q0 = csr[st0 + k + 2 + nz]; }
        if (k+1 < n1){ int p = q1; sv1 = *(const ushort4*)(hb + (unsigned)((p & 0x3FFFF) << 9) + c2); t1 = ((p >> 18) & 3)*256; if (k+2 < n1) q1 = csr[st1 + k + 2 + nz]; }
        if (k+1 < n2){ int p = q2; sv2 = *(const ushort4*)(hb + (unsigned)((p & 0x3FFFF) << 9) + c2); t2 = ((p >> 18) & 3)*256; if (k+2 < n2) q2 = csr[st2 + k + 2 + nz]; }
        if (k+1 < n3){ int p = q3; sv3 = *(const ushort4*)(hb + (unsigned)((p & 0x3FFFF) << 9) + c2); t3 = ((p >> 18) & 3)*256; if (k+2 < n3) q3 = csr[st3 + k + 2 + nz]; }
        if (k < n0){
          const float4 ev = *(const float4*)&ebs[u0 + c];
          float v;
          v = bf2f(c0.x) + ev.x; A0.x += v > 0.f ? v : 0.f;
          v = bf2f(c0.y) + ev.y; A0.y += v > 0.f ? v : 0.f;
          v = bf2f(c0.z) + ev.z; A0.z += v > 0.f ? v : 0.f;
          v = bf2f(c0.w) + ev.w; A0.w += v > 0.f ? v : 0.f;
        }
        if (k < n1){
          const float4 ev = *(const float4*)&ebs[u1 + c];
          float v;
          v = bf2f(c1.x) + ev.x; A1.x += v > 0.f ? v : 0.f;
          v = bf2f(c1.y) + ev.y; A1.y += v > 0.f ? v : 0.f;
          v = bf2f(c1.z) + ev.z; A1.z += v > 0.f ? v : 0.f;
          v = bf2f(c1.w) + ev.w; A1.w += v > 0.f ? v : 0.f;
        }
        if (k < n2){
          const float4 ev = *(const float4*)&ebs[u2 + c];
          float v;
          v = bf2f(c2v.x) + ev.x; A2.x += v > 0.f ? v : 0.f;
          v = bf2f(c2v.y) + ev.y; A2.y += v > 0.f ? v : 0.f;
          v = bf2f(c2v.z) + ev.z; A2.z += v > 0.f ? v : 0.f;
          v = bf2f(c2v.w) + ev.w; A2.w += v > 0.f ? v : 0.f;
        }
        if (k < n3){
          const float4 ev = *(const float4*)&ebs[u3 + c];
          float v;
          v = bf2f(c3.x) + ev.x; A3.x += v > 0.f ? v : 0.f;
          v = bf2f(c3.y) + ev.y; A3.y += v > 0.f ? v : 0.f;
          v = bf2f(c3.z) + ev.z; A3.z += v > 0.f ? v : 0.f;
          v = bf2f(c3.w) + ev.w; A3.w += v > 0.f ? v : 0.f;
        }
      }
      ushort4 o;
      o.x = f2bf(A0.x); o.y = f2bf(A0.y); o.z = f2bf(A0.z); o.w = f2bf(A0.w);
      *(ushort4*)&ZT[rr0+0][c] = o;
      o.x = f2bf(A1.x); o.y = f2bf(A1.y); o.z = f2bf(A1.z); o.w = f2bf(A1.w);
      *(ushort4*)&ZT[rr0+1][c] = o;
      o.x = f2bf(A2.x); o.y = f2bf(A2.y); o.z = f2bf(A2.z); o.w = f2bf(A2.w);
      *(ushort4*)&ZT[rr0+2][c] = o;
      o.x = f2bf(A3.x); o.y = f2bf(A3.y); o.z = f2bf(A3.z); o.w = f2bf(A3.w);
      *(ushort4*)&ZT[rr0+3][c] = o;
    }
  } else {
    const int c = l15 * 4;
    const unsigned c2 = l15 * 8;
    const int rrA = wv*8 + lq, rrB = rrA + 4;
    const int rA = rowBase + rrA, rB = rowBase + rrB;
    float aA0, aA1, aA2, aA3, aB0, aB1, aB2, aB3;
    {
      ushort4 hv = *(const ushort4*)(hb + (size_t)rA*128 + c2);
      aA0 = epv*bf2f(hv.x); aA1 = epv*bf2f(hv.y); aA2 = epv*bf2f(hv.z); aA3 = epv*bf2f(hv.w);
      hv = *(const ushort4*)(hb + (size_t)rB*128 + c2);
      aB0 = epv*bf2f(hv.x); aB1 = epv*bf2f(hv.y); aB2 = epv*bf2f(hv.z); aB3 = epv*bf2f(hv.w);
    }
    int stA = (rA == 0) ? 0 : Dend[rA-1], enA = Dend[rA];
    int stB = Dend[rB-1], enB = Dend[rB];
    int nA = enA - stA, nB = enB - stB;
    int nmax = nA > nB ? nA : nB;
    ushort4 svA, svB; int ttA = 0, ttB = 0, pA = 0, pB = 0;
    svA.x = svA.y = svA.z = svA.w = 0; svB = svA;
    if (nA > 0){ int p = csr[stA]; svA = *(const ushort4*)(hb + (unsigned)((p & 0x3FFFF) << 7) + c2); ttA = ((p >> 18) & 3)*64; }
    if (nB > 0){ int p = csr[stB]; svB = *(const ushort4*)(hb + (unsigned)((p & 0x3FFFF) << 7) + c2); ttB = ((p >> 18) & 3)*64; }
    if (nA > 1) pA = csr[stA+1];
    if (nB > 1) pB = csr[stB+1];
    for (int k = 0; k < nmax; k++){
      if (k < nA){
        ushort4 cu = svA;
        const float4 ev = *(const float4*)&ebs[ttA + c];
        if (k+1 < nA){
          int p = pA;
          svA = *(const ushort4*)(hb + (unsigned)((p & 0x3FFFF) << 7) + c2);
          ttA = ((p >> 18) & 3)*64;
          if (k+2 < nA) pA = csr[stA+k+2];
        }
        float v;
        v = bf2f(cu.x) + ev.x; aA0 += v > 0.f ? v : 0.f;
        v = bf2f(cu.y) + ev.y; aA1 += v > 0.f ? v : 0.f;
        v = bf2f(cu.z) + ev.z; aA2 += v > 0.f ? v : 0.f;
        v = bf2f(cu.w) + ev.w; aA3 += v > 0.f ? v : 0.f;
      }
      if (k < nB){
        ushort4 cu = svB;
        const float4 ev = *(const float4*)&ebs[ttB + c];
        if (k+1 < nB){
          int p = pB;
          svB = *(const ushort4*)(hb + (unsigned)((p & 0x3FFFF) << 7) + c2);
          ttB = ((p >> 18) & 3)*64;
          if (k+2 < nB) pB = csr[stB+k+2];
        }
        float v;
        v = bf2f(cu.x) + ev.x; aB0 += v > 0.f ? v : 0.f;
        v = bf2f(cu.y) + ev.y; aB1 += v > 0.f ? v : 0.f;
        v = bf2f(cu.z) + ev.z; aB2 += v > 0.f ? v : 0.f;
        v = bf2f(cu.w) + ev.w; aB3 += v > 0.f ? v : 0.f;
      }
    }
    ushort4 o;
    o.x = f2bf(aA0); o.y = f2bf(aA1); o.z = f2bf(aA2); o.w = f2bf(aA3);
    *(ushort4*)&ZT[rrA][c] = o;
    o.x = f2bf(aB0); o.y = f2bf(aB1); o.z = f2bf(aB2); o.w = f2bf(aB3);
    *(ushort4*)&ZT[rrB][c] = o;
  }
  __syncthreads();

  // ---- B: t = relu(z @ W1^T + b1), wave tile 32x64 ----
  f32x4 acc[2][4];
  #pragma unroll
  for (int i = 0; i < 2; i++)
    #pragma unroll
    for (int j = 0; j < 4; j++){ f32x4 z = {0.f,0.f,0.f,0.f}; acc[i][j] = z; }

  #pragma unroll
  for (int s = 0; s < KD/32; s++){
    short8 af[2], bfv[4];
    #pragma unroll
    for (int j = 0; j < 4; j++)
      bfv[j] = *(const short8*)(W1s + ((size_t)(s*16 + wv*4 + j)*64 + lane)*8);
    #pragma unroll
    for (int i = 0; i < 2; i++)
      af[i] = *(const short8*)&ZT[i*16 + l15][s*32 + lq*8];
    #pragma unroll
    for (int i = 0; i < 2; i++)
      #pragma unroll
      for (int j = 0; j < 4; j++)
        acc[i][j] = __builtin_amdgcn_mfma_f32_16x16x32_bf16(af[i], bfv[j], acc[i][j], 0, 0, 0);
  }
  __syncthreads();

  // ---- C: t -> ZT ----
  {
    float b1c[4];
    #pragma unroll
    for (int j = 0; j < 4; j++) b1c[j] = b1[wv*64 + j*16 + l15];
    #pragma unroll
    for (int i = 0; i < 2; i++)
      #pragma unroll
      for (int j = 0; j < 4; j++){
        int cc = wv*64 + j*16 + l15;
        #pragma unroll
        for (int rg = 0; rg < 4; rg++){
          int r = i*16 + (lq << 2) + rg;
          float v = acc[i][j][rg] + b1c[j];
          v = v > 0.f ? v : 0.f;
          ZT[r][cc] = f2bf(v);
        }
      }
  }
  __syncthreads();

  // ---- D: y = t @ W2^T ----
  #pragma unroll
  for (int i = 0; i < 2; i++)
    #pragma unroll
    for (int j = 0; j < 4; j++){ f32x4 z = {0.f,0.f,0.f,0.f}; acc[i][j] = z; }

  #pragma unroll
  for (int s = 0; s < 8; s++){
    short8 af[2], bfv[4];
    #pragma unroll
    for (int j = 0; j < 4; j++)
      bfv[j] = *(const short8*)(W2s + ((size_t)(s*16 + wv*4 + j)*64 + lane)*8);
    #pragma unroll
    for (int i = 0; i < 2; i++)
      af[i] = *(const short8*)&ZT[i*16 + l15][s*32 + lq*8];
    #pragma unroll
    for (int i = 0; i < 2; i++)
      #pragma unroll
      for (int j = 0; j < 4; j++)
        acc[i][j] = __builtin_amdgcn_mfma_f32_16x16x32_bf16(af[i], bfv[j], acc[i][j], 0, 0, 0);
  }

  // ---- E: LayerNorm stats ----
  float b2c[4];
  #pragma unroll
  for (int j = 0; j < 4; j++) b2c[j] = b2[wv*64 + j*16 + l15];
  #pragma unroll
  for (int i = 0; i < 2; i++){
    #pragma unroll
    for (int rg = 0; rg < 4; rg++){
      float s1 = 0.f, s2 = 0.f;
      #pragma unroll
      for (int j = 0; j < 4; j++){
        float y = acc[i][j][rg] + b2c[j];
        s1 += y; s2 += y*y;
      }
      #pragma unroll
      for (int m = 1; m < 16; m <<= 1){
        s1 += __shfl_xor(s1, m, 64);
        s2 += __shfl_xor(s2, m, 64);
      }
      if (l15 == 0){
        int r = i*16 + (lq << 2) + rg;
        red1[r][wv] = s1; red2[r][wv] = s2;
      }
    }
  }
  __syncthreads();
  if (tid < 32){
    float s1 = red1[tid][0] + red1[tid][1] + red1[tid][2] + red1[tid][3];
    float s2 = red2[tid][0] + red2[tid][1] + red2[tid][2] + red2[tid][3];
    float mn = s1 * (1.f/256.f);
    float vr = s2 * (1.f/256.f) - mn*mn;
    mnL[tid] = mn;
    rsL[tid] = rsqrtf(vr + 1e-5f);
  }
  __syncthreads();
  // ---- F: LN -> ZT ----
  #pragma unroll
  for (int i = 0; i < 2; i++){
    #pragma unroll
    for (int rg = 0; rg < 4; rg++){
      int r = i*16 + (lq << 2) + rg;
      float mn = mnL[r], rs = rsL[r];
      #pragma unroll
      for (int j = 0; j < 4; j++){
        int cc = wv*64 + j*16 + l15;
        float y = acc[i][j][rg] + b2c[j];
        float v = (y - mn) * rs;
        if (!RESID) v = v > 0.f ? v : 0.1f*v;
        ZT[r][cc] = f2bf(v);
      }
    }
  }
  __syncthreads();
  // ---- G: residual from HT (LDS) + leaky, coalesced store ----
  #pragma unroll
  for (int p = 0; p < 8; p++){
    int r = p*4 + (tid >> 6);
    int cs = (tid & 63) * 4;
    ushort4 zt = *(const ushort4*)&ZT[r][cs];
    ushort4 o;
    if (RESID){
      ushort4 rv = *(const ushort4*)&HT[r][cs];
      float v0 = bf2f(zt.x) + bf2f(rv.x);
      float v1 = bf2f(zt.y) + bf2f(rv.y);
      float v2 = bf2f(zt.z) + bf2f(rv.z);
      float v3 = bf2f(zt.w) + bf2f(rv.w);
      o.x = f2bf(v0 > 0.f ? v0 : 0.1f*v0);
      o.y = f2bf(v1 > 0.f ? v1 : 0.1f*v1);
      o.z = f2bf(v2 > 0.f ? v2 : 0.1f*v2);
      o.w = f2bf(v3 > 0.f ? v3 : 0.1f*v3);
    } else {
      o = zt;
    }
    *(ushort4*)(hout + (size_t)(rowBase + r)*256 + cs) = o;
  }
}

// ================= DIAGNOSTIC: phase A only (gather+z), stores gated opaque-false =================
// grid = 2*6250 -> row dur ~= 2x phase-A cost. No write traffic (gate never fires).
__global__ __launch_bounds__(256) void ablA_k(
    const ushort* __restrict__ hsrc, const int* __restrict__ Dend, const int* __restrict__ csr,
    const float* __restrict__ ebL, ushort* __restrict__ scratch)
{
  __shared__ ushort ZT[32][264];
  __shared__ float ebs[1024];
  const int tid = threadIdx.x, lane = tid & 63, wv = tid >> 6;
  int bb = blockIdx.x >= 6250 ? blockIdx.x - 6250 : blockIdx.x;
  const int rowBase = bb * 32;
  const float epv = 1.0f;
  const char* hb = (const char*)hsrc;

  for (int i = tid; i < 1024; i += 256) ebs[i] = ebL[i];
  __syncthreads();

  int nz; asm("v_mov_b32 %0, 0" : "=v"(nz));
  const int c = lane * 4;
  const unsigned c2 = lane * 8;
  #pragma unroll 1
  for (int it = 0; it < 2; it++){
    int rr0 = wv*8 + it*4;
    int r0 = rowBase + rr0;
    float4 A0, A1, A2, A3;
    {
      ushort4 q0 = *(const ushort4*)(hb + (size_t)(r0+0)*512 + c2);
      ushort4 q1 = *(const ushort4*)(hb + (size_t)(r0+1)*512 + c2);
      ushort4 q2 = *(const ushort4*)(hb + (size_t)(r0+2)*512 + c2);
      ushort4 q3 = *(const ushort4*)(hb + (size_t)(r0+3)*512 + c2);
      A0 = make_float4(epv*bf2f(q0.x), epv*bf2f(q0.y), epv*bf2f(q0.z), epv*bf2f(q0.w));
      A1 = make_float4(epv*bf2f(q1.x), epv*bf2f(q1.y), epv*bf2f(q1.z), epv*bf2f(q1.w));
      A2 = make_float4(epv*bf2f(q2.x), epv*bf2f(q2.y), epv*bf2f(q2.z), epv*bf2f(q2.w));
      A3 = make_float4(epv*bf2f(q3.x), epv*bf2f(q3.y), epv*bf2f(q3.z), epv*bf2f(q3.w));
    }
    int bm1 = (r0 == 0) ? 0 : Dend[r0-1];
    int e0 = Dend[r0], e1 = Dend[r0+1], e2 = Dend[r0+2], e3 = Dend[r0+3];
    int st0 = bm1, st1 = e0, st2 = e1, st3 = e2;
    int n0 = e0 - st0, n1 = e1 - st1, n2 = e2 - st2, n3 = e3 - st3;
    int nmax = n0 > n1 ? n0 : n1;
    nmax = nmax > n2 ? nmax : n2;
    nmax = nmax > n3 ? nmax : n3;
    ushort4 z4; z4.x = z4.y = z4.z = z4.w = 0;
    ushort4 sv0 = z4, sv1 = z4, sv2 = z4, sv3 = z4;
    int t0 = 0, t1 = 0, t2 = 0, t3 = 0;
    int q0 = 0, q1 = 0, q2 = 0, q3 = 0;
    if (n0 > 0){ int p = csr[st0 + nz]; sv0 = *(const ushort4*)(hb + (unsigned)((p & 0x3FFFF) << 9) + c2); t0 = ((p >> 18) & 3)*256; }
    if (n1 > 0){ int p = csr[st1 + nz]; sv1 = *(const ushort4*)(hb + (unsigned)((p & 0x3FFFF) << 9) + c2); t1 = ((p >> 18) & 3)*256; }
    if (n2 > 0){ int p = csr[st2 + nz]; sv2 = *(const ushort4*)(hb + (unsigned)((p & 0x3FFFF) << 9) + c2); t2 = ((p >> 18) & 3)*256; }
    if (n3 > 0){ int p = csr[st3 + nz]; sv3 = *(const ushort4*)(hb + (unsigned)((p & 0x3FFFF) << 9) + c2); t3 = ((p >> 18) & 3)*256; }
    if (n0 > 1) q0 = csr[st0 + 1 + nz];
    if (n1 > 1) q1 = csr[st1 + 1 + nz];
    if (n2 > 1) q2 = csr[st2 + 1 + nz];
    if (n3 > 1) q3 = csr[st3 + 1 + nz];
    for (int k = 0; k < nmax; k++){
      ushort4 c0 = sv0, c1 = sv1, c2v = sv2, c3 = sv3;
      int u0 = t0, u1 = t1, u2 = t2, u3 = t3;
      if (k+1 < n0){ int p = q0; sv0 = *(const ushort4*)(hb + (unsigned)((p & 0x3FFFF) << 9) + c2); t0 = ((p >> 18) & 3)*256; if (k+2 < n0) q0 = csr[st0 + k + 2 + nz]; }
      if (k+1 < n1){ int p = q1; sv1 = *(const ushort4*)(hb + (unsigned)((p & 0x3FFFF) << 9) + c2); t1 = ((p >> 18) & 3)*256; if (k+2 < n1) q1 = csr[st1 + k + 2 + nz]; }
      if (k+1 < n2){ int p = q2; sv2 = *(const ushort4*)(hb + (unsigned)((p & 0x3FFFF) << 9) + c2); t2 = ((p >> 18) & 3)*256; if (k+2 < n2) q2 = csr[st2 + k + 2 + nz]; }
      if (k+1 < n3){ int p = q3; sv3 = *(const ushort4*)(hb + (unsigned)((p & 0x3FFFF) << 9) + c2); t3 = ((p >> 18) & 3)*256; if (k+2 < n3) q3 = csr[st3 + k + 2 + nz]; }
      if (k < n0){
        const float4 ev = *(const float4*)&ebs[u0 + c];
        float v;
        v = bf2f(c0.x) + ev.x; A0.x += v > 0.f ? v : 0.f;
        v = bf2f(c0.y) + ev.y; A0.y += v > 0.f ? v : 0.f;
        v = bf2f(c0.z) + ev.z; A0.z += v > 0.f ? v : 0.f;
        v = bf2f(c0.w) + ev.w; A0.w += v > 0.f ? v : 0.f;
      }
      if (k < n1){
        const float4 ev = *(const float4*)&ebs[u1 + c];
        float v;
        v = bf2f(c1.x) + ev.x; A1.x += v > 0.f ? v : 0.f;
        v = bf2f(c1.y) + ev.y; A1.y += v > 0.f ? v : 0.f;
        v = bf2f(c1.z) + ev.z; A1.z += v > 0.f ? v : 0.f;
        v = bf2f(c1.w) + ev.w; A1.w += v > 0.f ? v : 0.f;
      }
      if (k < n2){
        const float4 ev = *(const float4*)&ebs[u2 + c];
        float v;
        v = bf2f(c2v.x) + ev.x; A2.x += v > 0.f ? v : 0.f;
        v = bf2f(c2v.y) + ev.y; A2.y += v > 0.f ? v : 0.f;
        v = bf2f(c2v.z) + ev.z; A2.z += v > 0.f ? v : 0.f;
        v = bf2f(c2v.w) + ev.w; A2.w += v > 0.f ? v : 0.f;
      }
      if (k < n3){
        const float4 ev = *(const float4*)&ebs[u3 + c];
        float v;
        v = bf2f(c3.x) + ev.x; A3.x += v > 0.f ? v : 0.f;
        v = bf2f(c3.y) + ev.y; A3.y += v > 0.f ? v : 0.f;
        v = bf2f(c3.z) + ev.z; A3.z += v > 0.f ? v : 0.f;
        v = bf2f(c3.w) + ev.w; A3.w += v > 0.f ? v : 0.f;
      }
    }
    ushort4 o;
    o.x = f2bf(A0.x); o.y = f2bf(A0.y); o.z = f2bf(A0.z); o.w = f2bf(A0.w);
    *(ushort4*)&ZT[rr0+0][c] = o;
    o.x = f2bf(A1.x); o.y = f2bf(A1.y); o.z = f2bf(A1.z); o.w = f2bf(A1.w);
    *(ushort4*)&ZT[rr0+1][c] = o;
    o.x = f2bf(A2.x); o.y = f2bf(A2.y); o.z = f2bf(A2.z); o.w = f2bf(A2.w);
    *(ushort4*)&ZT[rr0+2][c] = o;
    o.x = f2bf(A3.x); o.y = f2bf(A3.y); o.z = f2bf(A3.z); o.w = f2bf(A3.w);
    *(ushort4*)&ZT[rr0+3][c] = o;
  }
  __syncthreads();
  if (Dend[0] == -123456789){   // opaque-false: keeps work alive, never stores
    #pragma unroll
    for (int p = 0; p < 8; p++){
      int r = p*4 + (tid >> 6);
      int cs = (tid & 63) * 4;
      *(ushort4*)(scratch + (size_t)(rowBase + r)*256 + cs) = *(const ushort4*)&ZT[r][cs];
    }
  }
}

// ================= DIAGNOSTIC: phases B-F only (GEMM1+GEMM2+LN), gated store =================
// grid = 3*6250 -> row dur ~= 3x (BG compute + coalesced ZT fill). No write traffic.
__global__ __launch_bounds__(256) void ablBG_k(
    const ushort* __restrict__ zsrc,
    const ushort* __restrict__ W1s, const float* __restrict__ b1,
    const ushort* __restrict__ W2s, const float* __restrict__ b2,
    const int* __restrict__ Dend, ushort* __restrict__ scratch)
{
  __shared__ ushort ZT[32][264];
  __shared__ float red1[32][4], red2[32][4], mnL[32], rsL[32];
  const int tid = threadIdx.x, lane = tid & 63, wv = tid >> 6;
  const int l15 = lane & 15, lq = lane >> 4;
  int bb = blockIdx.x;
  if (bb >= 12500) bb -= 12500; else if (bb >= 6250) bb -= 6250;
  const int rowBase = bb * 32;

  // fill ZT coalesced (stand-in for phase A's output)
  #pragma unroll
  for (int p = 0; p < 8; p++){
    int r = p*4 + (tid >> 6);
    int cs = (tid & 63) * 4;
    *(ushort4*)&ZT[r][cs] = *(const ushort4*)(zsrc + (size_t)(rowBase + r)*256 + cs);
  }
  __syncthreads();

  // ---- B ----
  f32x4 acc[2][4];
  #pragma unroll
  for (int i = 0; i < 2; i++)
    #pragma unroll
    for (int j = 0; j < 4; j++){ f32x4 z = {0.f,0.f,0.f,0.f}; acc[i][j] = z; }
  #pragma unroll
  for (int s = 0; s < 8; s++){
    short8 af[2], bfv[4];
    #pragma unroll
    for (int j = 0; j < 4; j++)
      bfv[j] = *(const short8*)(W1s + ((size_t)(s*16 + wv*4 + j)*64 + lane)*8);
    #pragma unroll
    for (int i = 0; i < 2; i++)
      af[i] = *(const short8*)&ZT[i*16 + l15][s*32 + lq*8];
    #pragma unroll
    for (int i = 0; i < 2; i++)
      #pragma unroll
      for (int j = 0; j < 4; j++)
        acc[i][j] = __builtin_amdgcn_mfma_f32_16x16x32_bf16(af[i], bfv[j], acc[i][j], 0, 0, 0);
  }
  __syncthreads();
  // ---- C ----
  {
    float b1c[4];
    #pragma unroll
    for (int j = 0; j < 4; j++) b1c[j] = b1[wv*64 + j*16 + l15];
    #pragma unroll
    for (int i = 0; i < 2; i++)
      #pragma unroll
      for (int j = 0; j < 4; j++){
        int cc = wv*64 + j*16 + l15;
        #pragma unroll
        for (int rg = 0; rg < 4; rg++){
          int r = i*16 + (lq << 2) + rg;
          float v = acc[i][j][rg] + b1c[j];
          v = v > 0.f ? v : 0.f;
          ZT[r][cc] = f2bf(v);
        }
      }
  }
  __syncthreads();
  // ---- D ----
  #pragma unroll
  for (int i = 0; i < 2; i++)
    #pragma unroll
    for (int j = 0; j < 4; j++){ f32x4 z = {0.f,0.f,0.f,0.f}; acc[i][j] = z; }
  #pragma unroll
  for (int s = 0; s < 8; s++){
    short8 af[2], bfv[4];
    #pragma unroll
    for (int j = 0; j < 4; j++)
      bfv[j] = *(const short8*)(W2s + ((size_t)(s*16 + wv*4 + j)*64 + lane)*8);
    #pragma unroll
    for (int i = 0; i < 2; i++)
      af[i] = *(const short8*)&ZT[i*16 + l15][s*32 + lq*8];
    #pragma unroll
    for (int i = 0; i < 2; i++)
      #pragma unroll
      for (int j = 0; j < 4; j++)
        acc[i][j] = __builtin_amdgcn_mfma_f32_16x16x32_bf16(af[i], bfv[j], acc[i][j], 0, 0, 0);
  }
  // ---- E ----
  float b2c[4];
  #pragma unroll
  for (int j = 0; j < 4; j++) b2c[j] = b2[wv*64 + j*16 + l15];
  #pragma unroll
  for (int i = 0; i < 2; i++){
    #pragma unroll
    for (int rg = 0; rg < 4; rg++){
      float s1 = 0.f, s2 = 0.f;
      #pragma unroll
      for (int j = 0; j < 4; j++){
        float y = acc[i][j][rg] + b2c[j];
        s1 += y; s2 += y*y;
      }
      #pragma unroll
      for (int m = 1; m < 16; m <<= 1){
        s1 += __shfl_xor(s1, m, 64);
        s2 += __shfl_xor(s2, m, 64);
      }
      if (l15 == 0){
        int r = i*16 + (lq << 2) + rg;
        red1[r][wv] = s1; red2[r][wv] = s2;
      }
    }
  }
  __syncthreads();
  if (tid < 32){
    float s1 = red1[tid][0] + red1[tid][1] + red1[tid][2] + red1[tid][3];
    float s2 = red2[tid][0] + red2[tid][1] + red2[tid][2] + red2[tid][3];
    float mn = s1 * (1.f/256.f);
    float vr = s2 * (1.f/256.f) - mn*mn;
    mnL[tid] = mn;
    rsL[tid] = rsqrtf(vr + 1e-5f);
  }
  __syncthreads();
  // ---- F ----
  #pragma unroll
  for (int i = 0; i < 2; i++){
    #pragma unroll
    for (int rg = 0; rg < 4; rg++){
      int r = i*16 + (lq << 2) + rg;
      float mn = mnL[r], rs = rsL[r];
      #pragma unroll
      for (int j = 0; j < 4; j++){
        int cc = wv*64 + j*16 + l15;
        float y = acc[i][j][rg] + b2c[j];
        float v = (y - mn) * rs;
        v = v > 0.f ? v : 0.1f*v;
        ZT[r][cc] = f2bf(v);
      }
    }
  }
  __syncthreads();
  if (Dend[0] == -123456789){   // opaque-false gate
    #pragma unroll
    for (int p = 0; p < 8; p++){
      int r = p*4 + (tid >> 6);
      int cs = (tid & 63) * 4;
      *(ushort4*)(scratch + (size_t)(rowBase + r)*256 + cs) = *(const ushort4*)&ZT[r][cs];
    }
  }
}

// ---------------- readout -> catb bf16 (G x 384); row-parallel waves ----------------
__global__ __launch_bounds__(256) void readout_k(
    const ushort* __restrict__ h, const int* __restrict__ batch, const float* __restrict__ x,
    const int* __restrict__ sqlIds, const float* __restrict__ sqlMask,
    const float* __restrict__ tok, ushort* __restrict__ catb)
{
  int g = blockIdx.x, tid = threadIdx.x;
  const int lane = tid & 63, wv = tid >> 6;
  __shared__ int se[2];
  __shared__ float part[4][256];
  __shared__ float tpart[4][64];
  __shared__ float mpart[4];
  __shared__ float xs[2];
  if (tid < 2){
    int target = g + tid;
    int lo = 0, hi = NN;
    while (lo < hi){ int mid = (lo + hi) >> 1; if (batch[mid] < target) lo = mid + 1; else hi = mid; }
    se[tid] = lo;
  }
  __syncthreads();
  int start = se[0], end = se[1];
  {
    float a0 = 0.f, a1 = 0.f, a2 = 0.f, a3 = 0.f;
    for (int i = start + wv; i < end; i += 4){
      ushort4 q = *(const ushort4*)(h + (size_t)i*256 + lane*4);
      a0 += bf2f(q.x); a1 += bf2f(q.y); a2 += bf2f(q.z); a3 += bf2f(q.w);
    }
    part[wv][lane*4 + 0] = a0;
    part[wv][lane*4 + 1] = a1;
    part[wv][lane*4 + 2] = a2;
    part[wv][lane*4 + 3] = a3;
  }
  if (wv >= 2){
    int col = (wv == 2) ? 5 : 4;
    float s = 0.f;
    for (int i = start + lane; i < end; i += 64) s += x[(size_t)i*13 + col];
    #pragma unroll
    for (int m = 1; m < 64; m <<= 1) s += __shfl_xor(s, m, 64);
    if (lane == 0) xs[wv - 2] = s;
  }
  {
    int c = lane;
    float acc = 0.f, m = 0.f;
    for (int s = wv; s < 128; s += 4){
      int id = sqlIds[g*128 + s];
      float mk = sqlMask[g*128 + s];
      m += mk;
      acc += tok[(size_t)id*64 + c] * mk;
    }
    tpart[wv][c] = acc;
    if (c == 0) mpart[wv] = m;
  }
  __syncthreads();
  {
    float gsum = part[0][tid] + part[1][tid] + part[2][tid] + part[3][tid];
    catb[(size_t)g*384 + tid] = f2bf(gsum);
  }
  if (tid == 0){
    float cnt = (float)(end - start);
    float dn = cnt > 1.f ? cnt : 1.f;
    catb[(size_t)g*384 + 256] = f2bf(cnt);
    catb[(size_t)g*384 + 257] = f2bf(xs[0] / dn);
    catb[(size_t)g*384 + 258] = f2bf(xs[1] / dn);
  }
  if (tid < 64){
    float L = mpart[0] + mpart[1] + mpart[2] + mpart[3];
    L = L > 1.f ? L : 1.f;
    float tsum = tpart[0][tid] + tpart[1][tid] + tpart[2][tid] + tpart[3][tid];
    catb[(size_t)g*384 + 259 + tid] = f2bf(tsum / L);
  }
  if (tid >= 64 && tid < 125){
    catb[(size_t)g*384 + 259 + tid] = 0;   // zero pad 323..383
  }
}

// ---------------- head GEMM1: hid = leaky(catb @ mW1b^T + mb1), bf16 out ----------------
__global__ __launch_bounds__(256) void head1_k(
    const ushort* __restrict__ catb, const ushort* __restrict__ W1b,
    const float* __restrict__ b1, ushort* __restrict__ hidb)
{
  __shared__ ushort smem[64*72 + 256*72];
  ushort (*As)[72] = (ushort(*)[72])smem;
  ushort (*Ws)[72] = (ushort(*)[72])(smem + 64*72);
  const int tid = threadIdx.x, lane = tid & 63, wv = tid >> 6;
  const int rowBase = blockIdx.x * 64;
  f32x4 acc[4][4];
  #pragma unroll
  for (int i = 0; i < 4; i++)
    #pragma unroll
    for (int j = 0; j < 4; j++){ f32x4 z = {0.f,0.f,0.f,0.f}; acc[i][j] = z; }

  for (int k0 = 0; k0 < 384; k0 += 64){
    __syncthreads();
    #pragma unroll
    for (int p = 0; p < 4; p++){
      int r = p*16 + (tid >> 4);
      int kk = (tid & 15) * 4;
      *(ushort4*)&As[r][kk] = *(const ushort4*)(catb + (size_t)(rowBase + r)*384 + k0 + kk);
    }
    #pragma unroll
    for (int p = 0; p < 16; p++){
      int oc = p*16 + (tid >> 4);
      int kk = (tid & 15) * 4;
      *(ushort4*)&Ws[oc][kk] = *(const ushort4*)(W1b + (size_t)oc*384 + k0 + kk);
    }
    __syncthreads();
    #pragma unroll
    for (int kc = 0; kc < 2; kc++){
      short8 af[4], bfv[4];
      #pragma unroll
      for (int i = 0; i < 4; i++)
        af[i] = *(const short8*)&As[i*16 + (lane & 15)][kc*32 + (lane >> 4)*8];
      #pragma unroll
      for (int j = 0; j < 4; j++)
        bfv[j] = *(const short8*)&Ws[wv*64 + j*16 + (lane & 15)][kc*32 + (lane >> 4)*8];
      #pragma unroll
      for (int i = 0; i < 4; i++)
        #pragma unroll
        for (int j = 0; j < 4; j++)
          acc[i][j] = __builtin_amdgcn_mfma_f32_16x16x32_bf16(af[i], bfv[j], acc[i][j], 0, 0, 0);
    }
  }
  __syncthreads();
  ushort (*Cs)[264] = (ushort(*)[264])smem;
  #pragma unroll
  for (int j = 0; j < 4; j++){
    int cc = wv*64 + j*16 + (lane & 15);
    float bb = b1[cc];
    #pragma unroll
    for (int i = 0; i < 4; i++){
      #pragma unroll
      for (int rg = 0; rg < 4; rg++){
        int r = i*16 + ((lane >> 4) << 2) + rg;
        float v = acc[i][j][rg] + bb;
        v = v > 0.f ? v : 0.1f*v;
        Cs[r][cc] = f2bf(v);
      }
    }
  }
  __syncthreads();
  #pragma unroll
  for (int p = 0; p < 16; p++){
    int r = p*4 + (tid >> 6);
    int c = (tid & 63) * 4;
    *(ushort4*)(hidb + (size_t)(rowBase + r)*256 + c) = *(const ushort4*)&Cs[r][c];
  }
}

// ---------------- head GEMM2: out = hidb @ mW2b^T + mb2, fp32 out ----------------
__global__ __launch_bounds__(256) void head2_k(
    const ushort* __restrict__ hidb, const ushort* __restrict__ W2b,
    const float* __restrict__ b2, float* __restrict__ out)
{
  __shared__ float smemf[128*132];
  ushort (*As)[72] = (ushort(*)[72])smemf;
  ushort (*Bs)[72] = (ushort(*)[72])((ushort*)smemf + 128*72);
  const int tid = threadIdx.x, lane = tid & 63, wv = tid >> 6;
  const int wr = (wv >> 1) * 64;
  const int wc = (wv & 1) * 64;
  const int rowBase = blockIdx.x * 128;
  const int colBase = blockIdx.y * 128;
  const int lr = tid >> 4, lk = (tid & 15) * 4;

  f32x4 acc[4][4];
  #pragma unroll
  for (int i = 0; i < 4; i++)
    #pragma unroll
    for (int j = 0; j < 4; j++){ f32x4 z = {0.f,0.f,0.f,0.f}; acc[i][j] = z; }

  for (int k0 = 0; k0 < 256; k0 += 64){
    __syncthreads();
    #pragma unroll
    for (int p = 0; p < 8; p++){
      int r = lr + p*16;
      *(ushort4*)&As[r][lk] = *(const ushort4*)(hidb + (size_t)(rowBase + r)*256 + k0 + lk);
      *(ushort4*)&Bs[r][lk] = *(const ushort4*)(W2b + (size_t)(colBase + r)*256 + k0 + lk);
    }
    __syncthreads();
    #pragma unroll
    for (int kc = 0; kc < 2; kc++){
      short8 af[4], bfv[4];
      #pragma unroll
      for (int i = 0; i < 4; i++)
        af[i] = *(const short8*)&As[wr + i*16 + (lane & 15)][kc*32 + (lane >> 4)*8];
      #pragma unroll
      for (int j = 0; j < 4; j++)
        bfv[j] = *(const short8*)&Bs[wc + j*16 + (lane & 15)][kc*32 + (lane >> 4)*8];
      #pragma unroll
      for (int i = 0; i < 4; i++)
        #pragma unroll
        for (int j = 0; j < 4; j++)
          acc[i][j] = __builtin_amdgcn_mfma_f32_16x16x32_bf16(af[i], bfv[j], acc[i][j], 0, 0, 0);
    }
  }
  __syncthreads();
  float (*Cs)[132] = (float(*)[132])smemf;
  #pragma unroll
  for (int j = 0; j < 4; j++){
    int cl = wc + j*16 + (lane & 15);
    float bb = b2[colBase + cl];
    #pragma unroll
    for (int i = 0; i < 4; i++){
      int r0 = wr + i*16 + ((lane >> 4) << 2);
      #pragma unroll
      for (int rg = 0; rg < 4; rg++)
        Cs[r0 + rg][cl] = acc[i][j][rg] + bb;
    }
  }
  __syncthreads();
  #pragma unroll
  for (int p = 0; p < 16; p++){
    int r = (tid >> 5) + p*8;
    int c4 = (tid & 31) * 4;
    *(float4*)(out + (size_t)(rowBase + r)*512 + colBase + c4) = *(const float4*)&Cs[r][c4];
  }
}

extern "C" void kernel_launch(void* const* d_in, const int* in_sizes, int n_in,
                              void* d_out, int out_size, void* d_ws, size_t ws_size,
                              hipStream_t stream)
{
  const float* x       = (const float*)d_in[0];
  const int*   ei      = (const int*)d_in[1];
  const int*   src     = ei;
  const int*   dst     = ei + EE;
  const int*   eattr   = (const int*)d_in[2];
  const int*   batch   = (const int*)d_in[3];
  const int*   sqlIds  = (const int*)d_in[4];
  const float* sqlMask = (const float*)d_in[5];
  const float* opE     = (const float*)d_in[6];
  const float* eE      = (const float*)d_in[7];
  const float* tok     = (const float*)d_in[8];
  const float* lw0 = (const float*)d_in[9],  *lb0 = (const float*)d_in[10], *eps0 = (const float*)d_in[11];
  const float* W10 = (const float*)d_in[12], *b10 = (const float*)d_in[13];
  const float* W20 = (const float*)d_in[14], *b20 = (const float*)d_in[15];
  const float* lw1 = (const float*)d_in[16], *lb1 = (const float*)d_in[17], *eps1 = (const float*)d_in[18];
  const float* W11 = (const float*)d_in[19], *b11 = (const float*)d_in[20];
  const float* W21 = (const float*)d_in[21], *b21 = (const float*)d_in[22];
  const float* lw2 = (const float*)d_in[23], *lb2 = (const float*)d_in[24], *eps2 = (const float*)d_in[25];
  const float* W12 = (const float*)d_in[26], *b12 = (const float*)d_in[27];
  const float* W22 = (const float*)d_in[28], *b22 = (const float*)d_in[29];
  const float* mW1 = (const float*)d_in[30], *mb1 = (const float*)d_in[31];
  const float* mW2 = (const float*)d_in[32], *mb2 = (const float*)d_in[33];
  float* out = (float*)d_out;

  // ---- workspace layout ----
  char* ws = (char*)d_ws;
  size_t off = 0;
  const size_t NB256 = (size_t)NN*256*2;
  ushort* bufH    = (ushort*)(ws + off); off += NB256;   // h ping buffer
  char*   region  = ws + off;            off += NB256;   // h0 / h pong buffer / catb+hidb
  ushort* h0      = (ushort*)region;
  ushort* hPong   = (ushort*)region;
  ushort* catb    = (ushort*)region;
  ushort* hidb    = (ushort*)(region + (size_t)GG*384*2);
  ushort* wb10 = (ushort*)(ws + off); off += (size_t)256*64*2;
  ushort* wb20 = (ushort*)(ws + off); off += (size_t)65536*2;
  ushort* wb11 = (ushort*)(ws + off); off += (size_t)65536*2;
  ushort* wb21 = (ushort*)(ws + off); off += (size_t)65536*2;
  ushort* wb12 = (ushort*)(ws + off); off += (size_t)65536*2;
  ushort* wb22 = (ushort*)(ws + off); off += (size_t)65536*2;
  ushort* mW1b = (ushort*)(ws + off); off += (size_t)256*384*2;
  ushort* mW2b = (ushort*)(ws + off); off += (size_t)512*256*2;
  float*  eb   = (float*)(ws + off);  off += (size_t)3*4*256*4;
  int* D    = (int*)(ws + off); off += (size_t)NN*4;
  int* bsum = (int*)(ws + off); off += (size_t)NBLK*4;
  int* csr  = (int*)(ws + off); off += (size_t)EE*4;
  size_t needFast = off;

  if (ws_size < needFast) return;

  prep_k<<<2252, 256, 0, stream>>>(W10, W20, W11, W21, W12, W22,
                                   lw0, lb0, lw1, lb1, lw2, lb2, eE, mW1, mW2,
                                   wb10, wb20, wb11, wb21, wb12, wb22, mW1b, mW2b, eb);
  build_h0_k<<<50000, 256, 0, stream>>>(x, opE, h0);

  // ---- CSR build (by dst) ----
  hipMemsetAsync(D, 0, (size_t)NN*4, stream);
  deg_k<<<3125, 256, 0, stream>>>(dst, D);
  scan1_k<<<NBLK, 256, 0, stream>>>(D, bsum);
  scan2_k<<<1, 256, 0, stream>>>(bsum);
  scan3_k<<<NBLK, 256, 0, stream>>>(D, bsum);
  fill_k<<<3125, 256, 0, stream>>>(src, dst, eattr, D, csr); // D -> row ENDS

  // ---- fused layers (gather inside), ping-pong h ----
  layerf_k<64,0><<<6250, 256, 0, stream>>>(h0,    D, csr, eb,        wb10, b10, wb20, b20, eps0, bufH);
  layerf_k<256,1><<<6250, 256, 0, stream>>>(bufH, D, csr, eb + 1024, wb11, b11, wb21, b21, eps1, hPong);
  layerf_k<256,1><<<6250, 256, 0, stream>>>(hPong,D, csr, eb + 2048, wb12, b12, wb22, b22, eps2, bufH);

  // ---- readout + MFMA head ----
  readout_k<<<GG, 256, 0, stream>>>(bufH, batch, x, sqlIds, sqlMask, tok, catb);
  head1_k<<<32, 256, 0, stream>>>(catb, mW1b, mb1, hidb);
  head2_k<<<dim3(16, 4), 256, 0, stream>>>(hidb, mW2b, mb2, out);

  // ---- DIAGNOSTICS (after all production work; outputs gated off, cannot affect result) ----
  ablA_k<<<12500, 256, 0, stream>>>(bufH, D, csr, eb + 1024, hPong);
  ablBG_k<<<18750, 256, 0, stream>>>(bufH, wb11, b11, wb21, b21, D, hPong);
}

// Round 10
// 827.951 us; speedup vs baseline: 1.5066x; 1.5066x over previous
//
#include <hip/hip_runtime.h>

#define NN 200000
#define EE 800000
#define GG 2048
#define NBLK ((NN + 255) / 256)   // 782

typedef __attribute__((ext_vector_type(8))) short short8;
typedef __attribute__((ext_vector_type(4))) float f32x4;

__device__ __forceinline__ float bf2f(ushort u){
  unsigned x = ((unsigned)u) << 16;
  return __uint_as_float(x);
}
__device__ __forceinline__ ushort f2bf(float f){
  unsigned x = __float_as_uint(f);
  x += 0x7fffu + ((x >> 16) & 1u);
  return (ushort)(x >> 16);
}

// swizzle a 256xK fp32 weight into MFMA B-fragment order (K=256)
__device__ __forceinline__ void swz256(const float* __restrict__ W, ushort* __restrict__ o, int idx){
  int ks = idx >> 13, rem = idx & 8191;
  int j16 = rem >> 9, rem2 = rem & 511;
  int ln = rem2 >> 3, t = rem2 & 7;
  int row = j16*16 + (ln & 15);
  int k = ks*32 + (ln >> 4)*8 + t;
  o[idx] = f2bf(W[(size_t)row*256 + k]);
}

// ---------------- prep: weight conversion/swizzle + edge-bias tables ----------------
__global__ __launch_bounds__(256) void prep_k(
    const float* __restrict__ W10, const float* __restrict__ W20,
    const float* __restrict__ W11, const float* __restrict__ W21,
    const float* __restrict__ W12, const float* __restrict__ W22,
    const float* __restrict__ lw0, const float* __restrict__ lb0,
    const float* __restrict__ lw1, const float* __restrict__ lb1,
    const float* __restrict__ lw2, const float* __restrict__ lb2,
    const float* __restrict__ eE, const float* __restrict__ mW1,
    const float* __restrict__ mW2,
    ushort* __restrict__ wb10, ushort* __restrict__ wb20,
    ushort* __restrict__ wb11, ushort* __restrict__ wb21,
    ushort* __restrict__ wb12, ushort* __restrict__ wb22,
    ushort* __restrict__ mW1b, ushort* __restrict__ mW2b,
    float* __restrict__ eb)
{
  int b = blockIdx.x, tid = threadIdx.x;
  if (b < 64){ // W1_0 (256x44) -> B-frag swizzled 256x64 (2 kslices), zero-padded
    int idx = b*256 + tid;
    int ks = idx >> 13, rem = idx & 8191;
    int j16 = rem >> 9, rem2 = rem & 511;
    int ln = rem2 >> 3, t = rem2 & 7;
    int row = j16*16 + (ln & 15);
    int k = ks*32 + (ln >> 4)*8 + t;
    wb10[idx] = (k < 44) ? f2bf(W10[row*44 + k]) : (ushort)0;
    return;
  }
  b -= 64;
  if (b < 256){ swz256(W20, wb20, b*256+tid); return; } b -= 256;
  if (b < 256){ swz256(W11, wb11, b*256+tid); return; } b -= 256;
  if (b < 256){ swz256(W21, wb21, b*256+tid); return; } b -= 256;
  if (b < 256){ swz256(W12, wb12, b*256+tid); return; } b -= 256;
  if (b < 256){ swz256(W22, wb22, b*256+tid); return; } b -= 256;
  if (b < 384){ // mW1 (256x323) -> padded row-major (256x384)
    int idx = b*256 + tid; int o = idx / 384, k = idx - o*384;
    mW1b[idx] = (k < 323) ? f2bf(mW1[(size_t)o*323 + k]) : (ushort)0;
    return;
  }
  b -= 384;
  if (b < 512){ int idx = b*256+tid; mW2b[idx] = f2bf(mW2[idx]); return; } b -= 512;
  int li = b >> 2, t = b & 3;
  const float* lw = (li == 0) ? lw0 : ((li == 1) ? lw1 : lw2);
  const float* lb = (li == 0) ? lb0 : ((li == 1) ? lb1 : lb2);
  int d = (li == 0) ? 44 : 256;
  float v = 0.f;
  if (tid < d){
    float a = 0.f;
    #pragma unroll
    for (int j = 0; j < 16; j++) a += eE[t*16 + j] * lw[tid*16 + j];
    v = a + lb[tid];
  }
  eb[(li*4 + t)*256 + tid] = v;
}

// ---------------- h0 = [op_embed[op], nums, 0-pad] as bf16 N x 64 ----------------
__global__ __launch_bounds__(256) void build_h0_k(
    const float* __restrict__ x, const float* __restrict__ opE, ushort* __restrict__ h0)
{
  int idx = blockIdx.x*256 + threadIdx.x;
  int i = idx >> 6, c = idx & 63;
  float v = 0.f;
  if (c < 32){
    int op = (int)x[(size_t)i*13];
    op = op < 0 ? 0 : (op > 63 ? 63 : op);
    v = opE[op*32 + c];
  } else if (c < 44){
    v = x[(size_t)i*13 + (c - 31)];
  }
  h0[idx] = f2bf(v);
}

// ================= CSR build =================
__global__ __launch_bounds__(256) void deg_k(const int* __restrict__ dst, int* __restrict__ D){
  int e = blockIdx.x*256 + threadIdx.x;
  atomicAdd(&D[dst[e]], 1);
}
__global__ __launch_bounds__(256) void scan1_k(int* __restrict__ D, int* __restrict__ bsum){
  __shared__ int s[256];
  int b = blockIdx.x, t = threadIdx.x, idx = b*256 + t;
  int v = (idx < NN) ? D[idx] : 0;
  s[t] = v; __syncthreads();
  for (int off = 1; off < 256; off <<= 1){
    int u = (t >= off) ? s[t-off] : 0;
    __syncthreads();
    s[t] += u;
    __syncthreads();
  }
  if (idx < NN) D[idx] = s[t] - v;
  if (t == 255) bsum[b] = s[255];
}
__global__ __launch_bounds__(256) void scan2_k(int* __restrict__ bsum){
  __shared__ int s[256];
  __shared__ int carry;
  int t = threadIdx.x;
  if (t == 0) carry = 0;
  __syncthreads();
  for (int c0 = 0; c0 < NBLK; c0 += 256){
    int idx = c0 + t;
    int v = (idx < NBLK) ? bsum[idx] : 0;
    s[t] = v; __syncthreads();
    for (int off = 1; off < 256; off <<= 1){
      int u = (t >= off) ? s[t-off] : 0;
      __syncthreads();
      s[t] += u;
      __syncthreads();
    }
    int ex = s[t] - v + carry;
    if (idx < NBLK) bsum[idx] = ex;
    int tot = s[255];
    __syncthreads();
    if (t == 0) carry += tot;
    __syncthreads();
  }
}
__global__ __launch_bounds__(256) void scan3_k(int* __restrict__ D, const int* __restrict__ bsum){
  int b = blockIdx.x, idx = b*256 + threadIdx.x;
  if (idx < NN) D[idx] += bsum[b];
}
__global__ __launch_bounds__(256) void fill_k(const int* __restrict__ src, const int* __restrict__ dst,
                                              const int* __restrict__ et, int* __restrict__ D,
                                              int* __restrict__ csr){
  int e = blockIdx.x*256 + threadIdx.x;
  int d = dst[e];
  int t = et[e]; t = t < 3 ? t : 3;
  int pos = atomicAdd(&D[d], 1);
  csr[pos] = src[e] | (t << 18);
}

// ---------------- fused layer: gather + z + GEMM1 + GEMM2 + LN + resid + leaky ----------------
// R8 structure (32 rows/block, grid 6250, HT residual tile).
// NEW (R10): int8 per-row-scale shadow of h. WRS: phase G also emits a 256B/row
// offset-binary int8 image (q = rn(v*127/rowmax)+128) + per-row scale. RDS: phase A
// gathers 4B/lane from the shadow instead of 8B bf16 — halves the gather bytes on
// the ~2 TB/s random-read path that R9's ablation isolated as phase A's binding rate.
// Direct read / residual / GEMMs stay bf16.
template<int KD, int RESID, int WRS, int RDS>
__global__ __launch_bounds__(256) void layerf_k(
    const ushort* __restrict__ hsrc, const int* __restrict__ Dend, const int* __restrict__ csr,
    const float* __restrict__ ebL,
    const ushort* __restrict__ W1s, const float* __restrict__ b1,
    const ushort* __restrict__ W2s, const float* __restrict__ b2,
    const float* __restrict__ epsp, ushort* __restrict__ hout,
    const unsigned char* __restrict__ q8in, const float* __restrict__ sclin,
    unsigned char* __restrict__ q8out, float* __restrict__ sclout)
{
  __shared__ ushort ZT[32][264];
  __shared__ ushort HT[RESID ? 32 : 1][264];   // raw h_in tile for the residual
  __shared__ float ebs[1024];
  __shared__ float red1[32][4], red2[32][4], mnL[32], rsL[32];
  const int tid = threadIdx.x, lane = tid & 63, wv = tid >> 6;
  const int l15 = lane & 15, lq = lane >> 4;
  const int rowBase = blockIdx.x * 32;
  const float epv = 1.0f + epsp[0];
  const char* hb = (const char*)hsrc;

  if (KD == 256){
    for (int i = tid; i < 1024; i += 256) ebs[i] = ebL[i];
  } else {
    if (tid < 256) ebs[tid] = ebL[(tid >> 6)*256 + (tid & 63)];  // compact [4][64]
  }
  __syncthreads();

  // ---- A: z = (1+eps)h[r] + sum_e relu(h[src]+eb[et]) -> ZT ----
  if (KD == 256){
    int nz; asm("v_mov_b32 %0, 0" : "=v"(nz));  // opaque 0: csr loads on vector/vmcnt path
    const int c = lane * 4;         // element col
    const unsigned c2 = lane * 8;   // byte offset within bf16 row
    const unsigned c1 = lane * 4;   // byte offset within int8 row
    #pragma unroll 1
    for (int it = 0; it < 2; it++){
      int rr0 = wv*8 + it*4;
      int r0 = rowBase + rr0;
      float4 A0, A1, A2, A3;
      {
        ushort4 q0 = *(const ushort4*)(hb + (size_t)(r0+0)*512 + c2);
        ushort4 q1 = *(const ushort4*)(hb + (size_t)(r0+1)*512 + c2);
        ushort4 q2 = *(const ushort4*)(hb + (size_t)(r0+2)*512 + c2);
        ushort4 q3 = *(const ushort4*)(hb + (size_t)(r0+3)*512 + c2);
        if (RESID){
          *(ushort4*)&HT[rr0+0][c] = q0;
          *(ushort4*)&HT[rr0+1][c] = q1;
          *(ushort4*)&HT[rr0+2][c] = q2;
          *(ushort4*)&HT[rr0+3][c] = q3;
        }
        A0 = make_float4(epv*bf2f(q0.x), epv*bf2f(q0.y), epv*bf2f(q0.z), epv*bf2f(q0.w));
        A1 = make_float4(epv*bf2f(q1.x), epv*bf2f(q1.y), epv*bf2f(q1.z), epv*bf2f(q1.w));
        A2 = make_float4(epv*bf2f(q2.x), epv*bf2f(q2.y), epv*bf2f(q2.z), epv*bf2f(q2.w));
        A3 = make_float4(epv*bf2f(q3.x), epv*bf2f(q3.y), epv*bf2f(q3.z), epv*bf2f(q3.w));
      }
      int bm1 = (r0 == 0) ? 0 : Dend[r0-1];
      int e0 = Dend[r0], e1 = Dend[r0+1], e2 = Dend[r0+2], e3 = Dend[r0+3];
      int st0 = bm1, st1 = e0, st2 = e1, st3 = e2;
      int n0 = e0 - st0, n1 = e1 - st1, n2 = e2 - st2, n3 = e3 - st3;
      int nmax = n0 > n1 ? n0 : n1;
      nmax = nmax > n2 ? nmax : n2;
      nmax = nmax > n3 ? nmax : n3;

      if (RDS){
        // -------- int8-shadow gather: 4B/lane + per-row scale --------
        unsigned sv0 = 0, sv1 = 0, sv2 = 0, sv3 = 0;
        float ss0 = 0.f, ss1 = 0.f, ss2 = 0.f, ss3 = 0.f;
        int t0 = 0, t1 = 0, t2 = 0, t3 = 0;
        int q0 = 0, q1 = 0, q2 = 0, q3 = 0;   // 2-deep csr prefetch
        if (n0 > 0){ int p = csr[st0 + nz]; unsigned rw = (unsigned)(p & 0x3FFFF); sv0 = *(const unsigned*)(q8in + ((size_t)rw<<8) + c1); ss0 = sclin[rw]; t0 = ((p >> 18) & 3)*256; }
        if (n1 > 0){ int p = csr[st1 + nz]; unsigned rw = (unsigned)(p & 0x3FFFF); sv1 = *(const unsigned*)(q8in + ((size_t)rw<<8) + c1); ss1 = sclin[rw]; t1 = ((p >> 18) & 3)*256; }
        if (n2 > 0){ int p = csr[st2 + nz]; unsigned rw = (unsigned)(p & 0x3FFFF); sv2 = *(const unsigned*)(q8in + ((size_t)rw<<8) + c1); ss2 = sclin[rw]; t2 = ((p >> 18) & 3)*256; }
        if (n3 > 0){ int p = csr[st3 + nz]; unsigned rw = (unsigned)(p & 0x3FFFF); sv3 = *(const unsigned*)(q8in + ((size_t)rw<<8) + c1); ss3 = sclin[rw]; t3 = ((p >> 18) & 3)*256; }
        if (n0 > 1) q0 = csr[st0 + 1 + nz];
        if (n1 > 1) q1 = csr[st1 + 1 + nz];
        if (n2 > 1) q2 = csr[st2 + 1 + nz];
        if (n3 > 1) q3 = csr[st3 + 1 + nz];
        for (int k = 0; k < nmax; k++){
          unsigned c0 = sv0, c1v = sv1, c2v = sv2, c3v = sv3;
          float d0 = ss0, d1 = ss1, d2 = ss2, d3 = ss3;
          int u0 = t0, u1 = t1, u2 = t2, u3 = t3;
          if (k+1 < n0){ int p = q0; unsigned rw = (unsigned)(p & 0x3FFFF); sv0 = *(const unsigned*)(q8in + ((size_t)rw<<8) + c1); ss0 = sclin[rw]; t0 = ((p >> 18) & 3)*256; if (k+2 < n0) q0 = csr[st0 + k + 2 + nz]; }
          if (k+1 < n1){ int p = q1; unsigned rw = (unsigned)(p & 0x3FFFF); sv1 = *(const unsigned*)(q8in + ((size_t)rw<<8) + c1); ss1 = sclin[rw]; t1 = ((p >> 18) & 3)*256; if (k+2 < n1) q1 = csr[st1 + k + 2 + nz]; }
          if (k+1 < n2){ int p = q2; unsigned rw = (unsigned)(p & 0x3FFFF); sv2 = *(const unsigned*)(q8in + ((size_t)rw<<8) + c1); ss2 = sclin[rw]; t2 = ((p >> 18) & 3)*256; if (k+2 < n2) q2 = csr[st2 + k + 2 + nz]; }
          if (k+1 < n3){ int p = q3; unsigned rw = (unsigned)(p & 0x3FFFF); sv3 = *(const unsigned*)(q8in + ((size_t)rw<<8) + c1); ss3 = sclin[rw]; t3 = ((p >> 18) & 3)*256; if (k+2 < n3) q3 = csr[st3 + k + 2 + nz]; }
          if (k < n0){
            const float4 ev = *(const float4*)&ebs[u0 + c];
            float o = d0 * -128.f, v;
            v = fmaf((float)(c0 & 0xffu),        d0, o) + ev.x; A0.x += v > 0.f ? v : 0.f;
            v = fmaf((float)((c0 >> 8) & 0xffu), d0, o) + ev.y; A0.y += v > 0.f ? v : 0.f;
            v = fmaf((float)((c0 >> 16) & 0xffu),d0, o) + ev.z; A0.z += v > 0.f ? v : 0.f;
            v = fmaf((float)(c0 >> 24),          d0, o) + ev.w; A0.w += v > 0.f ? v : 0.f;
          }
          if (k < n1){
            const float4 ev = *(const float4*)&ebs[u1 + c];
            float o = d1 * -128.f, v;
            v = fmaf((float)(c1v & 0xffu),        d1, o) + ev.x; A1.x += v > 0.f ? v : 0.f;
            v = fmaf((float)((c1v >> 8) & 0xffu), d1, o) + ev.y; A1.y += v > 0.f ? v : 0.f;
            v = fmaf((float)((c1v >> 16) & 0xffu),d1, o) + ev.z; A1.z += v > 0.f ? v : 0.f;
            v = fmaf((float)(c1v >> 24),          d1, o) + ev.w; A1.w += v > 0.f ? v : 0.f;
          }
          if (k < n2){
            const float4 ev = *(const float4*)&ebs[u2 + c];
            float o = d2 * -128.f, v;
            v = fmaf((float)(c2v & 0xffu),        d2, o) + ev.x; A2.x += v > 0.f ? v : 0.f;
            v = fmaf((float)((c2v >> 8) & 0xffu), d2, o) + ev.y; A2.y += v > 0.f ? v : 0.f;
            v = fmaf((float)((c2v >> 16) & 0xffu),d2, o) + ev.z; A2.z += v > 0.f ? v : 0.f;
            v = fmaf((float)(c2v >> 24),          d2, o) + ev.w; A2.w += v > 0.f ? v : 0.f;
          }
          if (k < n3){
            const float4 ev = *(const float4*)&ebs[u3 + c];
            float o = d3 * -128.f, v;
            v = fmaf((float)(c3v & 0xffu),        d3, o) + ev.x; A3.x += v > 0.f ? v : 0.f;
            v = fmaf((float)((c3v >> 8) & 0xffu), d3, o) + ev.y; A3.y += v > 0.f ? v : 0.f;
            v = fmaf((float)((c3v >> 16) & 0xffu),d3, o) + ev.z; A3.z += v > 0.f ? v : 0.f;
            v = fmaf((float)(c3v >> 24),          d3, o) + ev.w; A3.w += v > 0.f ? v : 0.f;
          }
        }
      } else {
        // -------- original bf16 gather (R8) --------
        ushort4 z4; z4.x = z4.y = z4.z = z4.w = 0;
        ushort4 sv0 = z4, sv1 = z4, sv2 = z4, sv3 = z4;
        int t0 = 0, t1 = 0, t2 = 0, t3 = 0;
        int q0 = 0, q1 = 0, q2 = 0, q3 = 0;
        if (n0 > 0){ int p = csr[st0 + nz]; sv0 = *(const ushort4*)(hb + (unsigned)((p & 0x3FFFF) << 9) + c2); t0 = ((p >> 18) & 3)*256; }
        if (n1 > 0){ int p = csr[st1 + nz]; sv1 = *(const ushort4*)(hb + (unsigned)((p & 0x3FFFF) << 9) + c2); t1 = ((p >> 18) & 3)*256; }
        if (n2 > 0){ int p = csr[st2 + nz]; sv2 = *(const ushort4*)(hb + (unsigned)((p & 0x3FFFF) << 9) + c2); t2 = ((p >> 18) & 3)*256; }
        if (n3 > 0){ int p = csr[st3 + nz]; sv3 = *(const ushort4*)(hb + (unsigned)((p & 0x3FFFF) << 9) + c2); t3 = ((p >> 18) & 3)*256; }
        if (n0 > 1) q0 = csr[st0 + 1 + nz];
        if (n1 > 1) q1 = csr[st1 + 1 + nz];
        if (n2 > 1) q2 = csr[st2 + 1 + nz];
        if (n3 > 1) q3 = csr[st3 + 1 + nz];
        for (int k = 0; k < nmax; k++){
          ushort4 c0 = sv0, c1v = sv1, c2v = sv2, c3v = sv3;
          int u0 = t0, u1 = t1, u2 = t2, u3 = t3;
          if (k+1 < n0){ int p = q0; sv0 = *(const ushort4*)(hb + (unsigned)((p & 0x3FFFF) << 9) + c2); t0 = ((p >> 18) & 3)*256; if (k+2 < n0) q0 = csr[st0 + k + 2 + nz]; }
          if (k+1 < n1){ int p = q1; sv1 = *(const ushort4*)(hb + (unsigned)((p & 0x3FFFF) << 9) + c2); t1 = ((p >> 18) & 3)*256; if (k+2 < n1) q1 = csr[st1 + k + 2 + nz]; }
          if (k+1 < n2){ int p = q2; sv2 = *(const ushort4*)(hb + (unsigned)((p & 0x3FFFF) << 9) + c2); t2 = ((p >> 18) & 3)*256; if (k+2 < n2) q2 = csr[st2 + k + 2 + nz]; }
          if (k+1 < n3){ int p = q3; sv3 = *(const ushort4*)(hb + (unsigned)((p & 0x3FFFF) << 9) + c2); t3 = ((p >> 18) & 3)*256; if (k+2 < n3) q3 = csr[st3 + k + 2 + nz]; }
          if (k < n0){
            const float4 ev = *(const float4*)&ebs[u0 + c];
            float v;
            v = bf2f(c0.x) + ev.x; A0.x += v > 0.f ? v : 0.f;
            v = bf2f(c0.y) + ev.y; A0.y += v > 0.f ? v : 0.f;
            v = bf2f(c0.z) + ev.z; A0.z += v > 0.f ? v : 0.f;
            v = bf2f(c0.w) + ev.w; A0.w += v > 0.f ? v : 0.f;
          }
          if (k < n1){
            const float4 ev = *(const float4*)&ebs[u1 + c];
            float v;
            v = bf2f(c1v.x) + ev.x; A1.x += v > 0.f ? v : 0.f;
            v = bf2f(c1v.y) + ev.y; A1.y += v > 0.f ? v : 0.f;
            v = bf2f(c1v.z) + ev.z; A1.z += v > 0.f ? v : 0.f;
            v = bf2f(c1v.w) + ev.w; A1.w += v > 0.f ? v : 0.f;
          }
          if (k < n2){
            const float4 ev = *(const float4*)&ebs[u2 + c];
            float v;
            v = bf2f(c2v.x) + ev.x; A2.x += v > 0.f ? v : 0.f;
            v = bf2f(c2v.y) + ev.y; A2.y += v > 0.f ? v : 0.f;
            v = bf2f(c2v.z) + ev.z; A2.z += v > 0.f ? v : 0.f;
            v = bf2f(c2v.w) + ev.w; A2.w += v > 0.f ? v : 0.f;
          }
          if (k < n3){
            const float4 ev = *(const float4*)&ebs[u3 + c];
            float v;
            v = bf2f(c3v.x) + ev.x; A3.x += v > 0.f ? v : 0.f;
            v = bf2f(c3v.y) + ev.y; A3.y += v > 0.f ? v : 0.f;
            v = bf2f(c3v.z) + ev.z; A3.z += v > 0.f ? v : 0.f;
            v = bf2f(c3v.w) + ev.w; A3.w += v > 0.f ? v : 0.f;
          }
        }
      }
      ushort4 o;
      o.x = f2bf(A0.x); o.y = f2bf(A0.y); o.z = f2bf(A0.z); o.w = f2bf(A0.w);
      *(ushort4*)&ZT[rr0+0][c] = o;
      o.x = f2bf(A1.x); o.y = f2bf(A1.y); o.z = f2bf(A1.z); o.w = f2bf(A1.w);
      *(ushort4*)&ZT[rr0+1][c] = o;
      o.x = f2bf(A2.x); o.y = f2bf(A2.y); o.z = f2bf(A2.z); o.w = f2bf(A2.w);
      *(ushort4*)&ZT[rr0+2][c] = o;
      o.x = f2bf(A3.x); o.y = f2bf(A3.y); o.z = f2bf(A3.z); o.w = f2bf(A3.w);
      *(ushort4*)&ZT[rr0+3][c] = o;
    }
  } else {
    // KD==64: per-lane-quarter row streams (layer 0, bf16 h0 gather), 2-deep prefetch
    const int c = l15 * 4;
    const unsigned c2 = l15 * 8;
    const int rrA = wv*8 + lq, rrB = rrA + 4;
    const int rA = rowBase + rrA, rB = rowBase + rrB;
    float aA0, aA1, aA2, aA3, aB0, aB1, aB2, aB3;
    {
      ushort4 hv = *(const ushort4*)(hb + (size_t)rA*128 + c2);
      aA0 = epv*bf2f(hv.x); aA1 = epv*bf2f(hv.y); aA2 = epv*bf2f(hv.z); aA3 = epv*bf2f(hv.w);
      hv = *(const ushort4*)(hb + (size_t)rB*128 + c2);
      aB0 = epv*bf2f(hv.x); aB1 = epv*bf2f(hv.y); aB2 = epv*bf2f(hv.z); aB3 = epv*bf2f(hv.w);
    }
    int stA = (rA == 0) ? 0 : Dend[rA-1], enA = Dend[rA];
    int stB = Dend[rB-1], enB = Dend[rB];
    int nA = enA - stA, nB = enB - stB;
    int nmax = nA > nB ? nA : nB;
    ushort4 svA, svB; int ttA = 0, ttB = 0, pA = 0, pB = 0;
    svA.x = svA.y = svA.z = svA.w = 0; svB = svA;
    if (nA > 0){ int p = csr[stA]; svA = *(const ushort4*)(hb + (unsigned)((p & 0x3FFFF) << 7) + c2); ttA = ((p >> 18) & 3)*64; }
    if (nB > 0){ int p = csr[stB]; svB = *(const ushort4*)(hb + (unsigned)((p & 0x3FFFF) << 7) + c2); ttB = ((p >> 18) & 3)*64; }
    if (nA > 1) pA = csr[stA+1];
    if (nB > 1) pB = csr[stB+1];
    for (int k = 0; k < nmax; k++){
      if (k < nA){
        ushort4 cu = svA;
        const float4 ev = *(const float4*)&ebs[ttA + c];
        if (k+1 < nA){
          int p = pA;
          svA = *(const ushort4*)(hb + (unsigned)((p & 0x3FFFF) << 7) + c2);
          ttA = ((p >> 18) & 3)*64;
          if (k+2 < nA) pA = csr[stA+k+2];
        }
        float v;
        v = bf2f(cu.x) + ev.x; aA0 += v > 0.f ? v : 0.f;
        v = bf2f(cu.y) + ev.y; aA1 += v > 0.f ? v : 0.f;
        v = bf2f(cu.z) + ev.z; aA2 += v > 0.f ? v : 0.f;
        v = bf2f(cu.w) + ev.w; aA3 += v > 0.f ? v : 0.f;
      }
      if (k < nB){
        ushort4 cu = svB;
        const float4 ev = *(const float4*)&ebs[ttB + c];
        if (k+1 < nB){
          int p = pB;
          svB = *(const ushort4*)(hb + (unsigned)((p & 0x3FFFF) << 7) + c2);
          ttB = ((p >> 18) & 3)*64;
          if (k+2 < nB) pB = csr[stB+k+2];
        }
        float v;
        v = bf2f(cu.x) + ev.x; aB0 += v > 0.f ? v : 0.f;
        v = bf2f(cu.y) + ev.y; aB1 += v > 0.f ? v : 0.f;
        v = bf2f(cu.z) + ev.z; aB2 += v > 0.f ? v : 0.f;
        v = bf2f(cu.w) + ev.w; aB3 += v > 0.f ? v : 0.f;
      }
    }
    ushort4 o;
    o.x = f2bf(aA0); o.y = f2bf(aA1); o.z = f2bf(aA2); o.w = f2bf(aA3);
    *(ushort4*)&ZT[rrA][c] = o;
    o.x = f2bf(aB0); o.y = f2bf(aB1); o.z = f2bf(aB2); o.w = f2bf(aB3);
    *(ushort4*)&ZT[rrB][c] = o;
  }
  __syncthreads();

  // ---- B: t = relu(z @ W1^T + b1), wave tile 32x64 ----
  f32x4 acc[2][4];
  #pragma unroll
  for (int i = 0; i < 2; i++)
    #pragma unroll
    for (int j = 0; j < 4; j++){ f32x4 z = {0.f,0.f,0.f,0.f}; acc[i][j] = z; }

  #pragma unroll
  for (int s = 0; s < KD/32; s++){
    short8 af[2], bfv[4];
    #pragma unroll
    for (int j = 0; j < 4; j++)
      bfv[j] = *(const short8*)(W1s + ((size_t)(s*16 + wv*4 + j)*64 + lane)*8);
    #pragma unroll
    for (int i = 0; i < 2; i++)
      af[i] = *(const short8*)&ZT[i*16 + l15][s*32 + lq*8];
    #pragma unroll
    for (int i = 0; i < 2; i++)
      #pragma unroll
      for (int j = 0; j < 4; j++)
        acc[i][j] = __builtin_amdgcn_mfma_f32_16x16x32_bf16(af[i], bfv[j], acc[i][j], 0, 0, 0);
  }
  __syncthreads();

  // ---- C: t -> ZT ----
  {
    float b1c[4];
    #pragma unroll
    for (int j = 0; j < 4; j++) b1c[j] = b1[wv*64 + j*16 + l15];
    #pragma unroll
    for (int i = 0; i < 2; i++)
      #pragma unroll
      for (int j = 0; j < 4; j++){
        int cc = wv*64 + j*16 + l15;
        #pragma unroll
        for (int rg = 0; rg < 4; rg++){
          int r = i*16 + (lq << 2) + rg;
          float v = acc[i][j][rg] + b1c[j];
          v = v > 0.f ? v : 0.f;
          ZT[r][cc] = f2bf(v);
        }
      }
  }
  __syncthreads();

  // ---- D: y = t @ W2^T ----
  #pragma unroll
  for (int i = 0; i < 2; i++)
    #pragma unroll
    for (int j = 0; j < 4; j++){ f32x4 z = {0.f,0.f,0.f,0.f}; acc[i][j] = z; }

  #pragma unroll
  for (int s = 0; s < 8; s++){
    short8 af[2], bfv[4];
    #pragma unroll
    for (int j = 0; j < 4; j++)
      bfv[j] = *(const short8*)(W2s + ((size_t)(s*16 + wv*4 + j)*64 + lane)*8);
    #pragma unroll
    for (int i = 0; i < 2; i++)
      af[i] = *(const short8*)&ZT[i*16 + l15][s*32 + lq*8];
    #pragma unroll
    for (int i = 0; i < 2; i++)
      #pragma unroll
      for (int j = 0; j < 4; j++)
        acc[i][j] = __builtin_amdgcn_mfma_f32_16x16x32_bf16(af[i], bfv[j], acc[i][j], 0, 0, 0);
  }

  // ---- E: LayerNorm stats ----
  float b2c[4];
  #pragma unroll
  for (int j = 0; j < 4; j++) b2c[j] = b2[wv*64 + j*16 + l15];
  #pragma unroll
  for (int i = 0; i < 2; i++){
    #pragma unroll
    for (int rg = 0; rg < 4; rg++){
      float s1 = 0.f, s2 = 0.f;
      #pragma unroll
      for (int j = 0; j < 4; j++){
        float y = acc[i][j][rg] + b2c[j];
        s1 += y; s2 += y*y;
      }
      #pragma unroll
      for (int m = 1; m < 16; m <<= 1){
        s1 += __shfl_xor(s1, m, 64);
        s2 += __shfl_xor(s2, m, 64);
      }
      if (l15 == 0){
        int r = i*16 + (lq << 2) + rg;
        red1[r][wv] = s1; red2[r][wv] = s2;
      }
    }
  }
  __syncthreads();
  if (tid < 32){
    float s1 = red1[tid][0] + red1[tid][1] + red1[tid][2] + red1[tid][3];
    float s2 = red2[tid][0] + red2[tid][1] + red2[tid][2] + red2[tid][3];
    float mn = s1 * (1.f/256.f);
    float vr = s2 * (1.f/256.f) - mn*mn;
    mnL[tid] = mn;
    rsL[tid] = rsqrtf(vr + 1e-5f);
  }
  __syncthreads();
  // ---- F: LN -> ZT (leaky here only when no residual; resid+leaky fused into G) ----
  #pragma unroll
  for (int i = 0; i < 2; i++){
    #pragma unroll
    for (int rg = 0; rg < 4; rg++){
      int r = i*16 + (lq << 2) + rg;
      float mn = mnL[r], rs = rsL[r];
      #pragma unroll
      for (int j = 0; j < 4; j++){
        int cc = wv*64 + j*16 + l15;
        float y = acc[i][j][rg] + b2c[j];
        float v = (y - mn) * rs;
        if (!RESID) v = v > 0.f ? v : 0.1f*v;
        ZT[r][cc] = f2bf(v);
      }
    }
  }
  __syncthreads();
  // ---- G: residual from HT (LDS) + leaky, coalesced store; optional int8 shadow emit ----
  #pragma unroll
  for (int p = 0; p < 8; p++){
    int r = p*4 + (tid >> 6);
    int cs = (tid & 63) * 4;
    ushort4 zt = *(const ushort4*)&ZT[r][cs];
    float v0, v1, v2, v3;
    ushort4 o;
    if (RESID){
      ushort4 rv = *(const ushort4*)&HT[r][cs];
      v0 = bf2f(zt.x) + bf2f(rv.x);
      v1 = bf2f(zt.y) + bf2f(rv.y);
      v2 = bf2f(zt.z) + bf2f(rv.z);
      v3 = bf2f(zt.w) + bf2f(rv.w);
      v0 = v0 > 0.f ? v0 : 0.1f*v0;
      v1 = v1 > 0.f ? v1 : 0.1f*v1;
      v2 = v2 > 0.f ? v2 : 0.1f*v2;
      v3 = v3 > 0.f ? v3 : 0.1f*v3;
      o.x = f2bf(v0); o.y = f2bf(v1); o.z = f2bf(v2); o.w = f2bf(v3);
    } else {
      o = zt;
      v0 = bf2f(zt.x); v1 = bf2f(zt.y); v2 = bf2f(zt.z); v3 = bf2f(zt.w);
    }
    *(ushort4*)(hout + (size_t)(rowBase + r)*256 + cs) = o;
    if (WRS){
      float m = fmaxf(fmaxf(fabsf(v0), fabsf(v1)), fmaxf(fabsf(v2), fabsf(v3)));
      #pragma unroll
      for (int k = 1; k < 64; k <<= 1) m = fmaxf(m, __shfl_xor(m, k, 64));
      float inv = m > 0.f ? 127.f/m : 0.f;
      int grow = rowBase + r;
      if ((tid & 63) == 0) sclout[grow] = m * (1.f/127.f);
      int q0 = __float2int_rn(fmaf(v0, inv, 128.f));
      int q1 = __float2int_rn(fmaf(v1, inv, 128.f));
      int q2 = __float2int_rn(fmaf(v2, inv, 128.f));
      int q3 = __float2int_rn(fmaf(v3, inv, 128.f));
      q0 = q0 < 0 ? 0 : (q0 > 255 ? 255 : q0);
      q1 = q1 < 0 ? 0 : (q1 > 255 ? 255 : q1);
      q2 = q2 < 0 ? 0 : (q2 > 255 ? 255 : q2);
      q3 = q3 < 0 ? 0 : (q3 > 255 ? 255 : q3);
      unsigned dw = (unsigned)q0 | ((unsigned)q1 << 8) | ((unsigned)q2 << 16) | ((unsigned)q3 << 24);
      *(unsigned*)(q8out + (size_t)grow*256 + cs) = dw;
    }
  }
}

// ---------------- readout -> catb bf16 (G x 384); row-parallel waves ----------------
__global__ __launch_bounds__(256) void readout_k(
    const ushort* __restrict__ h, const int* __restrict__ batch, const float* __restrict__ x,
    const int* __restrict__ sqlIds, const float* __restrict__ sqlMask,
    const float* __restrict__ tok, ushort* __restrict__ catb)
{
  int g = blockIdx.x, tid = threadIdx.x;
  const int lane = tid & 63, wv = tid >> 6;
  __shared__ int se[2];
  __shared__ float part[4][256];
  __shared__ float tpart[4][64];
  __shared__ float mpart[4];
  __shared__ float xs[2];
  if (tid < 2){
    int target = g + tid;
    int lo = 0, hi = NN;
    while (lo < hi){ int mid = (lo + hi) >> 1; if (batch[mid] < target) lo = mid + 1; else hi = mid; }
    se[tid] = lo;
  }
  __syncthreads();
  int start = se[0], end = se[1];
  {
    float a0 = 0.f, a1 = 0.f, a2 = 0.f, a3 = 0.f;
    for (int i = start + wv; i < end; i += 4){
      ushort4 q = *(const ushort4*)(h + (size_t)i*256 + lane*4);
      a0 += bf2f(q.x); a1 += bf2f(q.y); a2 += bf2f(q.z); a3 += bf2f(q.w);
    }
    part[wv][lane*4 + 0] = a0;
    part[wv][lane*4 + 1] = a1;
    part[wv][lane*4 + 2] = a2;
    part[wv][lane*4 + 3] = a3;
  }
  if (wv >= 2){
    int col = (wv == 2) ? 5 : 4;
    float s = 0.f;
    for (int i = start + lane; i < end; i += 64) s += x[(size_t)i*13 + col];
    #pragma unroll
    for (int m = 1; m < 64; m <<= 1) s += __shfl_xor(s, m, 64);
    if (lane == 0) xs[wv - 2] = s;
  }
  {
    int c = lane;
    float acc = 0.f, m = 0.f;
    for (int s = wv; s < 128; s += 4){
      int id = sqlIds[g*128 + s];
      float mk = sqlMask[g*128 + s];
      m += mk;
      acc += tok[(size_t)id*64 + c] * mk;
    }
    tpart[wv][c] = acc;
    if (c == 0) mpart[wv] = m;
  }
  __syncthreads();
  {
    float gsum = part[0][tid] + part[1][tid] + part[2][tid] + part[3][tid];
    catb[(size_t)g*384 + tid] = f2bf(gsum);
  }
  if (tid == 0){
    float cnt = (float)(end - start);
    float dn = cnt > 1.f ? cnt : 1.f;
    catb[(size_t)g*384 + 256] = f2bf(cnt);
    catb[(size_t)g*384 + 257] = f2bf(xs[0] / dn);
    catb[(size_t)g*384 + 258] = f2bf(xs[1] / dn);
  }
  if (tid < 64){
    float L = mpart[0] + mpart[1] + mpart[2] + mpart[3];
    L = L > 1.f ? L : 1.f;
    float tsum = tpart[0][tid] + tpart[1][tid] + tpart[2][tid] + tpart[3][tid];
    catb[(size_t)g*384 + 259 + tid] = f2bf(tsum / L);
  }
  if (tid >= 64 && tid < 125){
    catb[(size_t)g*384 + 259 + tid] = 0;   // zero pad 323..383
  }
}

// ---------------- head GEMM1: hid = leaky(catb @ mW1b^T + mb1), bf16 out ----------------
__global__ __launch_bounds__(256) void head1_k(
    const ushort* __restrict__ catb, const ushort* __restrict__ W1b,
    const float* __restrict__ b1, ushort* __restrict__ hidb)
{
  __shared__ ushort smem[64*72 + 256*72];
  ushort (*As)[72] = (ushort(*)[72])smem;
  ushort (*Ws)[72] = (ushort(*)[72])(smem + 64*72);
  const int tid = threadIdx.x, lane = tid & 63, wv = tid >> 6;
  const int rowBase = blockIdx.x * 64;
  f32x4 acc[4][4];
  #pragma unroll
  for (int i = 0; i < 4; i++)
    #pragma unroll
    for (int j = 0; j < 4; j++){ f32x4 z = {0.f,0.f,0.f,0.f}; acc[i][j] = z; }

  for (int k0 = 0; k0 < 384; k0 += 64){
    __syncthreads();
    #pragma unroll
    for (int p = 0; p < 4; p++){
      int r = p*16 + (tid >> 4);
      int kk = (tid & 15) * 4;
      *(ushort4*)&As[r][kk] = *(const ushort4*)(catb + (size_t)(rowBase + r)*384 + k0 + kk);
    }
    #pragma unroll
    for (int p = 0; p < 16; p++){
      int oc = p*16 + (tid >> 4);
      int kk = (tid & 15) * 4;
      *(ushort4*)&Ws[oc][kk] = *(const ushort4*)(W1b + (size_t)oc*384 + k0 + kk);
    }
    __syncthreads();
    #pragma unroll
    for (int kc = 0; kc < 2; kc++){
      short8 af[4], bfv[4];
      #pragma unroll
      for (int i = 0; i < 4; i++)
        af[i] = *(const short8*)&As[i*16 + (lane & 15)][kc*32 + (lane >> 4)*8];
      #pragma unroll
      for (int j = 0; j < 4; j++)
        bfv[j] = *(const short8*)&Ws[wv*64 + j*16 + (lane & 15)][kc*32 + (lane >> 4)*8];
      #pragma unroll
      for (int i = 0; i < 4; i++)
        #pragma unroll
        for (int j = 0; j < 4; j++)
          acc[i][j] = __builtin_amdgcn_mfma_f32_16x16x32_bf16(af[i], bfv[j], acc[i][j], 0, 0, 0);
    }
  }
  __syncthreads();
  ushort (*Cs)[264] = (ushort(*)[264])smem;
  #pragma unroll
  for (int j = 0; j < 4; j++){
    int cc = wv*64 + j*16 + (lane & 15);
    float bb = b1[cc];
    #pragma unroll
    for (int i = 0; i < 4; i++){
      #pragma unroll
      for (int rg = 0; rg < 4; rg++){
        int r = i*16 + ((lane >> 4) << 2) + rg;
        float v = acc[i][j][rg] + bb;
        v = v > 0.f ? v : 0.1f*v;
        Cs[r][cc] = f2bf(v);
      }
    }
  }
  __syncthreads();
  #pragma unroll
  for (int p = 0; p < 16; p++){
    int r = p*4 + (tid >> 6);
    int c = (tid & 63) * 4;
    *(ushort4*)(hidb + (size_t)(rowBase + r)*256 + c) = *(const ushort4*)&Cs[r][c];
  }
}

// ---------------- head GEMM2: out = hidb @ mW2b^T + mb2, fp32 out ----------------
__global__ __launch_bounds__(256) void head2_k(
    const ushort* __restrict__ hidb, const ushort* __restrict__ W2b,
    const float* __restrict__ b2, float* __restrict__ out)
{
  __shared__ float smemf[128*132];
  ushort (*As)[72] = (ushort(*)[72])smemf;
  ushort (*Bs)[72] = (ushort(*)[72])((ushort*)smemf + 128*72);
  const int tid = threadIdx.x, lane = tid & 63, wv = tid >> 6;
  const int wr = (wv >> 1) * 64;
  const int wc = (wv & 1) * 64;
  const int rowBase = blockIdx.x * 128;
  const int colBase = blockIdx.y * 128;
  const int lr = tid >> 4, lk = (tid & 15) * 4;

  f32x4 acc[4][4];
  #pragma unroll
  for (int i = 0; i < 4; i++)
    #pragma unroll
    for (int j = 0; j < 4; j++){ f32x4 z = {0.f,0.f,0.f,0.f}; acc[i][j] = z; }

  for (int k0 = 0; k0 < 256; k0 += 64){
    __syncthreads();
    #pragma unroll
    for (int p = 0; p < 8; p++){
      int r = lr + p*16;
      *(ushort4*)&As[r][lk] = *(const ushort4*)(hidb + (size_t)(rowBase + r)*256 + k0 + lk);
      *(ushort4*)&Bs[r][lk] = *(const ushort4*)(W2b + (size_t)(colBase + r)*256 + k0 + lk);
    }
    __syncthreads();
    #pragma unroll
    for (int kc = 0; kc < 2; kc++){
      short8 af[4], bfv[4];
      #pragma unroll
      for (int i = 0; i < 4; i++)
        af[i] = *(const short8*)&As[wr + i*16 + (lane & 15)][kc*32 + (lane >> 4)*8];
      #pragma unroll
      for (int j = 0; j < 4; j++)
        bfv[j] = *(const short8*)&Bs[wc + j*16 + (lane & 15)][kc*32 + (lane >> 4)*8];
      #pragma unroll
      for (int i = 0; i < 4; i++)
        #pragma unroll
        for (int j = 0; j < 4; j++)
          acc[i][j] = __builtin_amdgcn_mfma_f32_16x16x32_bf16(af[i], bfv[j], acc[i][j], 0, 0, 0);
    }
  }
  __syncthreads();
  float (*Cs)[132] = (float(*)[132])smemf;
  #pragma unroll
  for (int j = 0; j < 4; j++){
    int cl = wc + j*16 + (lane & 15);
    float bb = b2[colBase + cl];
    #pragma unroll
    for (int i = 0; i < 4; i++){
      int r0 = wr + i*16 + ((lane >> 4) << 2);
      #pragma unroll
      for (int rg = 0; rg < 4; rg++)
        Cs[r0 + rg][cl] = acc[i][j][rg] + bb;
    }
  }
  __syncthreads();
  #pragma unroll
  for (int p = 0; p < 16; p++){
    int r = (tid >> 5) + p*8;
    int c4 = (tid & 31) * 4;
    *(float4*)(out + (size_t)(rowBase + r)*512 + colBase + c4) = *(const float4*)&Cs[r][c4];
  }
}

extern "C" void kernel_launch(void* const* d_in, const int* in_sizes, int n_in,
                              void* d_out, int out_size, void* d_ws, size_t ws_size,
                              hipStream_t stream)
{
  const float* x       = (const float*)d_in[0];
  const int*   ei      = (const int*)d_in[1];
  const int*   src     = ei;
  const int*   dst     = ei + EE;
  const int*   eattr   = (const int*)d_in[2];
  const int*   batch   = (const int*)d_in[3];
  const int*   sqlIds  = (const int*)d_in[4];
  const float* sqlMask = (const float*)d_in[5];
  const float* opE     = (const float*)d_in[6];
  const float* eE      = (const float*)d_in[7];
  const float* tok     = (const float*)d_in[8];
  const float* lw0 = (const float*)d_in[9],  *lb0 = (const float*)d_in[10], *eps0 = (const float*)d_in[11];
  const float* W10 = (const float*)d_in[12], *b10 = (const float*)d_in[13];
  const float* W20 = (const float*)d_in[14], *b20 = (const float*)d_in[15];
  const float* lw1 = (const float*)d_in[16], *lb1 = (const float*)d_in[17], *eps1 = (const float*)d_in[18];
  const float* W11 = (const float*)d_in[19], *b11 = (const float*)d_in[20];
  const float* W21 = (const float*)d_in[21], *b21 = (const float*)d_in[22];
  const float* lw2 = (const float*)d_in[23], *lb2 = (const float*)d_in[24], *eps2 = (const float*)d_in[25];
  const float* W12 = (const float*)d_in[26], *b12 = (const float*)d_in[27];
  const float* W22 = (const float*)d_in[28], *b22 = (const float*)d_in[29];
  const float* mW1 = (const float*)d_in[30], *mb1 = (const float*)d_in[31];
  const float* mW2 = (const float*)d_in[32], *mb2 = (const float*)d_in[33];
  float* out = (float*)d_out;

  // ---- workspace layout ----
  char* ws = (char*)d_ws;
  size_t off = 0;
  const size_t NB256 = (size_t)NN*256*2;
  ushort* bufH    = (ushort*)(ws + off); off += NB256;   // h ping buffer
  char*   region  = ws + off;            off += NB256;   // h0 / h pong buffer / catb+hidb
  ushort* h0      = (ushort*)region;
  ushort* hPong   = (ushort*)region;
  ushort* catb    = (ushort*)region;
  ushort* hidb    = (ushort*)(region + (size_t)GG*384*2);
  ushort* wb10 = (ushort*)(ws + off); off += (size_t)256*64*2;
  ushort* wb20 = (ushort*)(ws + off); off += (size_t)65536*2;
  ushort* wb11 = (ushort*)(ws + off); off += (size_t)65536*2;
  ushort* wb21 = (ushort*)(ws + off); off += (size_t)65536*2;
  ushort* wb12 = (ushort*)(ws + off); off += (size_t)65536*2;
  ushort* wb22 = (ushort*)(ws + off); off += (size_t)65536*2;
  ushort* mW1b = (ushort*)(ws + off); off += (size_t)256*384*2;
  ushort* mW2b = (ushort*)(ws + off); off += (size_t)512*256*2;
  float*  eb   = (float*)(ws + off);  off += (size_t)3*4*256*4;
  int* D    = (int*)(ws + off); off += (size_t)NN*4;
  int* bsum = (int*)(ws + off); off += (size_t)NBLK*4;
  int* csr  = (int*)(ws + off); off += (size_t)EE*4;
  size_t needFast = off;

  // int8 shadow region (optional; fall back to bf16-only path if ws is too small)
  unsigned char* q8A = (unsigned char*)(ws + off); off += (size_t)NN*256;
  float* sclA = (float*)(ws + off); off += (size_t)NN*4;
  unsigned char* q8B = (unsigned char*)(ws + off); off += (size_t)NN*256;
  float* sclB = (float*)(ws + off); off += (size_t)NN*4;
  size_t needShadow = off;

  if (ws_size < needFast) return;
  const bool useShad = (ws_size >= needShadow);

  prep_k<<<2252, 256, 0, stream>>>(W10, W20, W11, W21, W12, W22,
                                   lw0, lb0, lw1, lb1, lw2, lb2, eE, mW1, mW2,
                                   wb10, wb20, wb11, wb21, wb12, wb22, mW1b, mW2b, eb);
  build_h0_k<<<50000, 256, 0, stream>>>(x, opE, h0);

  // ---- CSR build (by dst) ----
  hipMemsetAsync(D, 0, (size_t)NN*4, stream);
  deg_k<<<3125, 256, 0, stream>>>(dst, D);
  scan1_k<<<NBLK, 256, 0, stream>>>(D, bsum);
  scan2_k<<<1, 256, 0, stream>>>(bsum);
  scan3_k<<<NBLK, 256, 0, stream>>>(D, bsum);
  fill_k<<<3125, 256, 0, stream>>>(src, dst, eattr, D, csr); // D -> row ENDS

  // ---- fused layers (gather inside), ping-pong h ----
  if (useShad){
    layerf_k<64,0,1,0><<<6250, 256, 0, stream>>>(h0,    D, csr, eb,        wb10, b10, wb20, b20, eps0, bufH,
                                                 nullptr, nullptr, q8A, sclA);
    layerf_k<256,1,1,1><<<6250, 256, 0, stream>>>(bufH, D, csr, eb + 1024, wb11, b11, wb21, b21, eps1, hPong,
                                                 q8A, sclA, q8B, sclB);
    layerf_k<256,1,0,1><<<6250, 256, 0, stream>>>(hPong,D, csr, eb + 2048, wb12, b12, wb22, b22, eps2, bufH,
                                                 q8B, sclB, nullptr, nullptr);
  } else {
    layerf_k<64,0,0,0><<<6250, 256, 0, stream>>>(h0,    D, csr, eb,        wb10, b10, wb20, b20, eps0, bufH,
                                                 nullptr, nullptr, nullptr, nullptr);
    layerf_k<256,1,0,0><<<6250, 256, 0, stream>>>(bufH, D, csr, eb + 1024, wb11, b11, wb21, b21, eps1, hPong,
                                                 nullptr, nullptr, nullptr, nullptr);
    layerf_k<256,1,0,0><<<6250, 256, 0, stream>>>(hPong,D, csr, eb + 2048, wb12, b12, wb22, b22, eps2, bufH,
                                                 nullptr, nullptr, nullptr, nullptr);
  }

  // ---- readout + MFMA head ----
  readout_k<<<GG, 256, 0, stream>>>(bufH, batch, x, sqlIds, sqlMask, tok, catb);
  head1_k<<<32, 256, 0, stream>>>(catb, mW1b, mb1, hidb);
  head2_k<<<dim3(16, 4), 256, 0, stream>>>(hidb, mW2b, mb2, out);
}